// Round 20
// baseline (363.217 us; speedup 1.0000x reference)
//
#include <hip/hip_runtime.h>
#include <hip/hip_bf16.h>
#include <stdint.h>

#define NEXP 16
#define KSEL 4
#define HDIM 2048
#define IDIM 1024
#define TTOK 2048
#define MAXTILES 80
#define NTA 8                    // gemmA n-tiles (IDIM/128)
#define NTB 16                   // gemmB n-tiles (HDIM/128)
#define MAXBA (MAXTILES * NTA)   // 640
#define MAXBB (MAXTILES * NTB)   // 1280
#define NCVT 1024                // piggyback cvt blocks per stream
#define NW8 ((NEXP * IDIM * HDIM) / 8)

typedef __attribute__((ext_vector_type(8))) short bf16x8;
typedef __attribute__((ext_vector_type(4))) float f32x4;
typedef __attribute__((ext_vector_type(4))) unsigned int u32x4;
typedef unsigned int u32;

__device__ __forceinline__ uint32_t pack2(float a, float b) {
  __hip_bfloat162 h = __float22bfloat162_rn(float2{a, b});
  uint32_t u;
  __builtin_memcpy(&u, &h, 4);
  return u;
}
__device__ __forceinline__ ushort bf1(float a) {
  __hip_bfloat16 h = __float2bfloat16(a);
  ushort u;
  __builtin_memcpy(&u, &h, 2);
  return u;
}
__device__ __forceinline__ float bf2f(ushort u) {
  uint32_t v = (uint32_t)u << 16;
  float f;
  __builtin_memcpy(&f, &v, 4);
  return f;
}
// async global->LDS, 16B per lane; linear dest, per-lane (gathered/swizzled)
// source address (m97/m173 pattern).
__device__ __forceinline__ void gload16(const void* g, void* l) {
  __builtin_amdgcn_global_load_lds(
      (const __attribute__((address_space(1))) u32*)g,
      (__attribute__((address_space(3))) u32*)l, 16, 0, 0);
}
// bf16 tile [rows][32 bf16]: stored linear, source chunk pre-XOR'd,
// read chunk XOR'd -> conflict-free (0 conflicts verified R3-R19).
__device__ __forceinline__ int swzread(int row, int q) {
  return row * 32 + ((q ^ ((row >> 1) & 3)) << 3);
}
// fp32 -> bf16 streaming body (NT loads), grid-strided over nblk blocks.
__device__ __forceinline__ void cvt_body(const float* __restrict__ src,
                                         ushort* __restrict__ dst,
                                         int blk, int nblk) {
  const int stride = nblk * 256;
  for (int i = blk * 256 + (int)threadIdx.x; i < NW8; i += stride) {
    f32x4 a = __builtin_nontemporal_load(((const f32x4*)src) + i * 2);
    f32x4 b = __builtin_nontemporal_load(((const f32x4*)src) + i * 2 + 1);
    uint4 t;
    t.x = pack2(a[0], a[1]); t.y = pack2(a[2], a[3]);
    t.z = pack2(b[0], b[1]); t.w = pack2(b[2], b[3]);
    ((uint4*)dst)[i] = t;
  }
}

// -- router (blocks 0..511) + piggyback cvt w1g AND cvt w1u (blocks 512+) --
__global__ __launch_bounds__(256) void router_kernel(
    const float* __restrict__ x, const float* __restrict__ gw,
    ushort* __restrict__ xb, int* __restrict__ topk_id,
    float* __restrict__ topk_w,
    const float* __restrict__ srcG, ushort* __restrict__ dstG,
    const float* __restrict__ srcU, ushort* __restrict__ dstU)
{
  if (blockIdx.x >= TTOK / 4 + NCVT) {
    cvt_body(srcU, dstU, blockIdx.x - (TTOK / 4 + NCVT), NCVT);
    return;
  }
  if (blockIdx.x >= TTOK / 4) {
    cvt_body(srcG, dstG, blockIdx.x - TTOK / 4, NCVT);
    return;
  }
  const int wid = threadIdx.x >> 6;
  const int lane = threadIdx.x & 63;
  const int t = blockIdx.x * 4 + wid;
  const float4* x4 = (const float4*)(x + (size_t)t * HDIM);
  const float4* gw4 = (const float4*)gw;
  float acc[NEXP];
#pragma unroll
  for (int e = 0; e < NEXP; ++e) acc[e] = 0.f;
#pragma unroll
  for (int i = 0; i < HDIM / 256; ++i) {
    const int idx = i * 64 + lane;
    float4 xv = x4[idx];
    uint2 xp;
    xp.x = pack2(xv.x, xv.y);
    xp.y = pack2(xv.z, xv.w);
    *(uint2*)(xb + (size_t)t * HDIM + idx * 4) = xp;
#pragma unroll
    for (int e = 0; e < NEXP; ++e) {
      float4 wv = gw4[e * (HDIM / 4) + idx];
      acc[e] += xv.x * wv.x + xv.y * wv.y + xv.z * wv.z + xv.w * wv.w;
    }
  }
#pragma unroll
  for (int e = 0; e < NEXP; ++e) {
#pragma unroll
    for (int off = 32; off >= 1; off >>= 1)
      acc[e] += __shfl_xor(acc[e], off);
  }
  if (lane == 0) {
    unsigned taken = 0;
    float vals[KSEL];
    int ids[KSEL];
#pragma unroll
    for (int k = 0; k < KSEL; ++k) {
      float bv = -3.4e38f; int bi = 0;
      for (int e = 0; e < NEXP; ++e)
        if (!((taken >> e) & 1u) && acc[e] > bv) { bv = acc[e]; bi = e; }
      taken |= 1u << bi; vals[k] = bv; ids[k] = bi;
    }
    float m = vals[0], s = 0.f, w[KSEL];
#pragma unroll
    for (int k = 0; k < KSEL; ++k) { w[k] = __expf(vals[k] - m); s += w[k]; }
    float is = 1.f / s;
#pragma unroll
    for (int k = 0; k < KSEL; ++k) {
      topk_id[t * KSEL + k] = ids[k];
      topk_w[t * KSEL + k] = w[k] * is;
    }
  }
}

// --- plan+scatter, single block: LDS histogram/cursors, no global atomics --
__global__ __launch_bounds__(1024) void plan_scatter_kernel(
    const int* __restrict__ topk_id, int* __restrict__ counts,
    int* __restrict__ offsets, int* __restrict__ nWA, int* __restrict__ nWB,
    int* __restrict__ wlA, int* __restrict__ wlB,
    int* __restrict__ rowTok, int* __restrict__ inv)
{
  __shared__ int cnt[NEXP], off[NEXP], cur[NEXP], tiles[NEXP], pre[NEXP];
  const int tid = threadIdx.x;
  if (tid < NEXP) { cnt[tid] = 0; cur[tid] = 0; }
  __syncthreads();
  for (int i = tid; i < TTOK * KSEL; i += 1024)
    atomicAdd(&cnt[topk_id[i]], 1);               // LDS atomics (fast)
  __syncthreads();
  if (tid == 0) {
    int s = 0, p = 0;
    for (int e = 0; e < NEXP; ++e) {
      off[e] = s; s += cnt[e];
      tiles[e] = (cnt[e] + 127) >> 7;
      pre[e] = p; p += tiles[e];
    }
    *nWA = p * NTA;
    *nWB = p * NTB;
  }
  __syncthreads();
  if (tid < NEXP) {
    counts[tid] = cnt[tid];
    offsets[tid] = off[tid];
    const int e = tid, T = tiles[e];
    int idx = pre[e] * NTA;
    for (int nt = 0; nt < NTA; ++nt)
      for (int mt = 0; mt < T; ++mt)
        wlA[idx++] = (e << 12) | (nt << 6) | mt;
  } else if (tid < 2 * NEXP) {
    const int e = tid - NEXP, T = tiles[e];
    int idx = pre[e] * NTB;
    for (int nt = 0; nt < NTB; ++nt)
      for (int mt = 0; mt < T; ++mt)
        wlB[idx++] = (e << 12) | (nt << 6) | mt;
  }
  for (int i = tid; i < TTOK * KSEL; i += 1024) {
    const int e = topk_id[i];
    const int pos = atomicAdd(&cur[e], 1);        // LDS atomic
    const int row = off[e] + pos;
    rowTok[row] = i >> 2;
    inv[i] = row;
  }
}

// -- gemmA split-K merged: 4*MAXBA GEMM blocks
//    seg0: gate k-half0 -> gp0   seg1: gate k-half1 -> gp1
//    seg2: up   k-half0 -> up0   seg3: up   k-half1 -> up1
//    + NCVT blocks: cvt(w2). fp32 partial outputs; silu does the reduce.
//    Pristine R15 GEMM body, NTK=32, uniform entry select. ---------------
__global__ __launch_bounds__(256) void gemmA_kernel(
    const ushort* __restrict__ xb,
    const ushort* __restrict__ wG, const ushort* __restrict__ wU,
    float* __restrict__ gp0, float* __restrict__ gp1,
    float* __restrict__ up0, float* __restrict__ up1,
    const int* __restrict__ rowTok, const int* __restrict__ counts,
    const int* __restrict__ offsets, const int* __restrict__ nW,
    const int* __restrict__ wl,
    const float* __restrict__ cvsrc, ushort* __restrict__ cvdst)
{
  int bid = blockIdx.x;
  if (bid >= 4 * MAXBA) {
    cvt_body(cvsrc, cvdst, bid - 4 * MAXBA, NCVT);
    return;
  }
  const int seg = bid / MAXBA;          // 0..3 (uniform)
  bid -= seg * MAXBA;
  const int kh = seg & 1;               // k-half
  const ushort* wb = (seg >> 1) ? wU : wG;
  float* outp = (seg == 0) ? gp0 : (seg == 1) ? gp1 : (seg == 2) ? up0 : up1;

  const int nTot = *nW;
  const int L = (bid & 7) * (MAXBA / 8) + (bid >> 3);
  if (L >= nTot) return;
  const int w = wl[L];
  const int e = w >> 12, nt = (w >> 6) & 63, mt = w & 63;
  const int n_e = counts[e], rowbase = offsets[e];

  __shared__ ushort As[2][128 * 32];
  __shared__ ushort Bs[2][128 * 32];

  const int tid = threadIdx.x;
  const int r0 = tid >> 2;
  const int ck = tid & 3;
  const int sch = (ck ^ ((r0 >> 1) & 3)) << 3;
  const int kbase = kh * (HDIM / 2);    // element offset of this K-half

  const int ar0 = mt * 128 + r0, ar1 = ar0 + 64;
  const int tok0 = rowTok[rowbase + (ar0 < n_e ? ar0 : n_e - 1)];
  const int tok1 = rowTok[rowbase + (ar1 < n_e ? ar1 : n_e - 1)];
  const ushort* pA0 = xb + (size_t)tok0 * HDIM + kbase + sch;
  const ushort* pA1 = xb + (size_t)tok1 * HDIM + kbase + sch;
  const size_t wbase = (size_t)e * IDIM * HDIM;
  const ushort* pB0 = wb + wbase + (size_t)(nt * 128 + r0) * HDIM + kbase + sch;
  const ushort* pB1 = wb + wbase + (size_t)(nt * 128 + r0 + 64) * HDIM + kbase + sch;

  const int lane = tid & 63;
  const int wid = tid >> 6;
  const int wr = (wid >> 1) << 6;
  const int wc = (wid & 1) << 6;
  const int lr = lane & 15;
  const int q = lane >> 4;

  f32x4 acc[4][4];
#pragma unroll
  for (int i = 0; i < 4; ++i)
#pragma unroll
    for (int j = 0; j < 4; ++j) acc[i][j] = (f32x4){0.f, 0.f, 0.f, 0.f};

  auto STAGE = [&](int b) {
    gload16(pA0, &As[b][tid * 8]);
    gload16(pA1, &As[b][2048 + tid * 8]);
    gload16(pB0, &Bs[b][tid * 8]);
    gload16(pB1, &Bs[b][2048 + tid * 8]);
    pA0 += 32; pA1 += 32; pB0 += 32; pB1 += 32;
  };

  const int NTK = HDIM / 64;  // 32 (half of K)
  STAGE(0);
  __syncthreads();
  int buf = 0;
  for (int kt = 0; kt < NTK; ++kt) {
    if (kt + 1 < NTK) STAGE(buf ^ 1);
    bf16x8 af[4], bfr[4];
#pragma unroll
    for (int mi = 0; mi < 4; ++mi)
      af[mi] = *(const bf16x8*)&As[buf][swzread(wr + mi * 16 + lr, q)];
#pragma unroll
    for (int ni = 0; ni < 4; ++ni)
      bfr[ni] = *(const bf16x8*)&Bs[buf][swzread(wc + ni * 16 + lr, q)];
#pragma unroll
    for (int mi = 0; mi < 4; ++mi)
#pragma unroll
      for (int ni = 0; ni < 4; ++ni)
        acc[mi][ni] = __builtin_amdgcn_mfma_f32_16x16x32_bf16(af[mi], bfr[ni], acc[mi][ni], 0, 0, 0);
    __syncthreads();
    buf ^= 1;
  }

#pragma unroll
  for (int mi = 0; mi < 4; ++mi) {
#pragma unroll
    for (int ni = 0; ni < 4; ++ni) {
      const int col = nt * 128 + wc + ni * 16 + lr;
#pragma unroll
      for (int r = 0; r < 4; ++r) {
        const int mrow = mt * 128 + wr + mi * 16 + q * 4 + r;
        if (mrow < n_e)
          outp[(size_t)(rowbase + mrow) * IDIM + col] = acc[mi][ni][r];
      }
    }
  }
}

// ------- gemmB: po[rows][2048] = hbuf . w2^T  (pristine R15 body) -------
__global__ __launch_bounds__(256) void gemmB_kernel(
    const ushort* __restrict__ hb, const ushort* __restrict__ wb,
    const int* __restrict__ counts, const int* __restrict__ offsets,
    const int* __restrict__ nW, const int* __restrict__ wl,
    ushort* __restrict__ po)
{
  const int nTot = *nW;
  const int L = (blockIdx.x & 7) * (MAXBB / 8) + (blockIdx.x >> 3);
  if (L >= nTot) return;
  const int w = wl[L];
  const int e = w >> 12, nt = (w >> 6) & 63, mt = w & 63;
  const int n_e = counts[e], rowbase = offsets[e];

  __shared__ ushort As[2][128 * 32];
  __shared__ ushort Bs[2][128 * 32];

  const int tid = threadIdx.x;
  const int r0 = tid >> 2;
  const int ck = tid & 3;
  const int sch = (ck ^ ((r0 >> 1) & 3)) << 3;

  const int ar0 = mt * 128 + r0, ar1 = ar0 + 64;
  const int g0 = rowbase + (ar0 < n_e ? ar0 : n_e - 1);
  const int g1 = rowbase + (ar1 < n_e ? ar1 : n_e - 1);
  const ushort* pA0 = hb + (size_t)g0 * IDIM + sch;
  const ushort* pA1 = hb + (size_t)g1 * IDIM + sch;
  const size_t wbase = (size_t)e * HDIM * IDIM;
  const ushort* pB0 = wb + wbase + (size_t)(nt * 128 + r0) * IDIM + sch;
  const ushort* pB1 = wb + wbase + (size_t)(nt * 128 + r0 + 64) * IDIM + sch;

  const int lane = tid & 63;
  const int wid = tid >> 6;
  const int wr = (wid >> 1) << 6;
  const int wc = (wid & 1) << 6;
  const int lr = lane & 15;
  const int q = lane >> 4;

  f32x4 acc[4][4];
#pragma unroll
  for (int i = 0; i < 4; ++i)
#pragma unroll
    for (int j = 0; j < 4; ++j) acc[i][j] = (f32x4){0.f, 0.f, 0.f, 0.f};

  auto STAGE = [&](int b) {
    gload16(pA0, &As[b][tid * 8]);
    gload16(pA1, &As[b][2048 + tid * 8]);
    gload16(pB0, &Bs[b][tid * 8]);
    gload16(pB1, &Bs[b][2048 + tid * 8]);
    pA0 += 32; pA1 += 32; pB0 += 32; pB1 += 32;
  };

  const int NTK = IDIM / 32;  // 32
  STAGE(0);
  __syncthreads();
  int buf = 0;
  for (int kt = 0; kt < NTK; ++kt) {
    if (kt + 1 < NTK) STAGE(buf ^ 1);
    bf16x8 af[4], bfr[4];
#pragma unroll
    for (int mi = 0; mi < 4; ++mi)
      af[mi] = *(const bf16x8*)&As[buf][swzread(wr + mi * 16 + lr, q)];
#pragma unroll
    for (int ni = 0; ni < 4; ++ni)
      bfr[ni] = *(const bf16x8*)&Bs[buf][swzread(wc + ni * 16 + lr, q)];
#pragma unroll
    for (int mi = 0; mi < 4; ++mi)
#pragma unroll
      for (int ni = 0; ni < 4; ++ni)
        acc[mi][ni] = __builtin_amdgcn_mfma_f32_16x16x32_bf16(af[mi], bfr[ni], acc[mi][ni], 0, 0, 0);
    __syncthreads();
    buf ^= 1;
  }

#pragma unroll
  for (int mi = 0; mi < 4; ++mi) {
#pragma unroll
    for (int ni = 0; ni < 4; ++ni) {
      const int col = nt * 128 + wc + ni * 16 + lr;
#pragma unroll
      for (int r = 0; r < 4; ++r) {
        const int mrow = mt * 128 + wr + mi * 16 + q * 4 + r;
        if (mrow < n_e)
          po[(size_t)(rowbase + mrow) * HDIM + col] = bf1(acc[mi][ni][r]);
      }
    }
  }
}

// --- silu+reduce: h = silu(g0+g1) * (u0+u1), fp32 partials -> bf16 -------
__global__ __launch_bounds__(256) void silu_kernel(
    const float* __restrict__ g0p, const float* __restrict__ g1p,
    const float* __restrict__ u0p, const float* __restrict__ u1p,
    ushort* __restrict__ h, int n4)
{
  const int stride = gridDim.x * 256;
  for (int i = blockIdx.x * 256 + threadIdx.x; i < n4; i += stride) {
    f32x4 a = __builtin_nontemporal_load(((const f32x4*)g0p) + i);
    f32x4 b = __builtin_nontemporal_load(((const f32x4*)g1p) + i);
    f32x4 c = __builtin_nontemporal_load(((const f32x4*)u0p) + i);
    f32x4 d = __builtin_nontemporal_load(((const f32x4*)u1p) + i);
    uint2 hv;
#pragma unroll
    for (int wd = 0; wd < 2; ++wd) {
      const float ga = a[wd * 2] + b[wd * 2];
      const float gb = a[wd * 2 + 1] + b[wd * 2 + 1];
      const float ua = c[wd * 2] + d[wd * 2];
      const float ub = c[wd * 2 + 1] + d[wd * 2 + 1];
      const float h0 = (ga / (1.f + __expf(-ga))) * ua;
      const float h1 = (gb / (1.f + __expf(-gb))) * ub;
      (&hv.x)[wd] = pack2(h0, h1);
    }
    ((uint2*)h)[i] = hv;
  }
}

// ---------------- combine: out[t] = sum_k w_k * po[row_k] -----------------
__global__ __launch_bounds__(256) void combine_kernel(
    const ushort* __restrict__ po, const int* __restrict__ inv,
    const float* __restrict__ tw, float* __restrict__ out)
{
  const int t = blockIdx.x;
  const int r0 = inv[t * 4 + 0], r1 = inv[t * 4 + 1];
  const int r2 = inv[t * 4 + 2], r3 = inv[t * 4 + 3];
  const float w0 = tw[t * 4 + 0], w1 = tw[t * 4 + 1];
  const float w2v = tw[t * 4 + 2], w3 = tw[t * 4 + 3];
  const int i = threadIdx.x;
  uint4 v0 = *(const uint4*)(po + (size_t)r0 * HDIM + i * 8);
  uint4 v1 = *(const uint4*)(po + (size_t)r1 * HDIM + i * 8);
  uint4 v2 = *(const uint4*)(po + (size_t)r2 * HDIM + i * 8);
  uint4 v3 = *(const uint4*)(po + (size_t)r3 * HDIM + i * 8);
  float o[8];
#pragma unroll
  for (int w = 0; w < 4; ++w) {
    const uint32_t a = (&v0.x)[w], b = (&v1.x)[w], c = (&v2.x)[w], d = (&v3.x)[w];
    o[w * 2 + 0] = w0 * __builtin_bit_cast(float, a << 16) +
                   w1 * __builtin_bit_cast(float, b << 16) +
                   w2v * __builtin_bit_cast(float, c << 16) +
                   w3 * __builtin_bit_cast(float, d << 16);
    o[w * 2 + 1] = w0 * __builtin_bit_cast(float, a & 0xffff0000u) +
                   w1 * __builtin_bit_cast(float, b & 0xffff0000u) +
                   w2v * __builtin_bit_cast(float, c & 0xffff0000u) +
                   w3 * __builtin_bit_cast(float, d & 0xffff0000u);
  }
  float4* o4 = (float4*)(out + (size_t)t * HDIM + i * 8);
  o4[0] = (float4){o[0], o[1], o[2], o[3]};
  o4[1] = (float4){o[4], o[5], o[6], o[7]};
}

extern "C" void kernel_launch(void* const* d_in, const int* in_sizes, int n_in,
                              void* d_out, int out_size, void* d_ws, size_t ws_size,
                              hipStream_t stream) {
  const float* x   = (const float*)d_in[0];
  const float* gw  = (const float*)d_in[1];
  const float* w1g = (const float*)d_in[2];
  const float* w1u = (const float*)d_in[3];
  const float* w2  = (const float*)d_in[4];
  float* out = (float*)d_out;

  char* ws = (char*)d_ws;
  // layout (bytes): xb 8MB @0; wbufG 64MB @8M; wbufU 64MB @72M;
  // wbuf2 64MB @136M; gp0 32MB @200M; gp1 32MB @232M; up0 32MB @264M;
  // up1 32MB @296M; hbuf 16MB @328M; po 32MB @344M; idx @376M; ctrl.
  ushort* xb    = (ushort*)(ws + 0);
  ushort* wbufG = (ushort*)(ws + 8388608);
  ushort* wbufU = (ushort*)(ws + 75497472);
  ushort* wbuf2 = (ushort*)(ws + 142606336);
  float*  gp0   = (float*) (ws + 209715200);
  float*  gp1   = (float*) (ws + 243269632);
  float*  up0   = (float*) (ws + 276824064);
  float*  up1   = (float*) (ws + 310378496);
  ushort* hbuf  = (ushort*)(ws + 343932928);
  ushort* po    = (ushort*)(ws + 360710144);
  int*    tkid   = (int*)(ws + 394264576);
  float*  tkw    = (float*)(ws + 394264576 + 32768);
  int*    rowTok = (int*)(ws + 394264576 + 65536);
  int*    inv    = (int*)(ws + 394264576 + 98304);
  int*    ctrl   = (int*)(ws + 394395648);
  int* counts  = ctrl;           // 16
  int* offsets = ctrl + 32;      // 17
  int* nWA     = ctrl + 50;      // 1
  int* nWB     = ctrl + 51;      // 1
  int* wlA     = ctrl + 64;      // MAXBA (640)
  int* wlB     = ctrl + 64 + MAXBA;  // MAXBB (1280)

  // router + cvt(w1g) + cvt(w1u) overlap
  router_kernel<<<TTOK / 4 + 2 * NCVT, 256, 0, stream>>>(
      x, gw, xb, tkid, tkw, w1g, wbufG, w1u, wbufU);
  plan_scatter_kernel<<<1, 1024, 0, stream>>>(tkid, counts, offsets, nWA, nWB,
                                              wlA, wlB, rowTok, inv);
  // split-K gate+up GEMM (4 segments) + cvt(w2) overlap
  gemmA_kernel<<<4 * MAXBA + NCVT, 256, 0, stream>>>(
      xb, wbufG, wbufU, gp0, gp1, up0, up1, rowTok, counts, offsets, nWA, wlA,
      w2, wbuf2);
  // h = silu(g0+g1) * (u0+u1)  (split-K reduce fused)
  silu_kernel<<<2048, 256, 0, stream>>>(gp0, gp1, up0, up1, hbuf,
                                        (TTOK * KSEL * IDIM) / 4);
  // down pass (reads wbuf2)
  gemmB_kernel<<<MAXBB, 256, 0, stream>>>(hbuf, wbuf2, counts, offsets,
                                          nWB, wlB, po);
  combine_kernel<<<TTOK, 256, 0, stream>>>(po, inv, tkw, out);
}

// Round 21
// 326.290 us; speedup vs baseline: 1.1132x; 1.1132x over previous
//
#include <hip/hip_runtime.h>
#include <hip/hip_bf16.h>
#include <stdint.h>

#define NEXP 16
#define KSEL 4
#define HDIM 2048
#define IDIM 1024
#define TTOK 2048
#define MAXTILES 80
#define NT1 16                   // gemm1 n-tiles (IDIM/64): 64 G-cols + 64 U-cols per block
#define NTB 16                   // gemmB n-tiles (HDIM/128)
#define MAXB1 (MAXTILES * NT1)   // 1280
#define MAXBB (MAXTILES * NTB)   // 1280
#define NCVT 1024                // piggyback cvt blocks per stream
#define NW8 ((NEXP * IDIM * HDIM) / 8)

typedef __attribute__((ext_vector_type(8))) short bf16x8;
typedef __attribute__((ext_vector_type(4))) float f32x4;
typedef __attribute__((ext_vector_type(4))) unsigned int u32x4;
typedef unsigned int u32;

__device__ __forceinline__ uint32_t pack2(float a, float b) {
  __hip_bfloat162 h = __float22bfloat162_rn(float2{a, b});
  uint32_t u;
  __builtin_memcpy(&u, &h, 4);
  return u;
}
__device__ __forceinline__ ushort bf1(float a) {
  __hip_bfloat16 h = __float2bfloat16(a);
  ushort u;
  __builtin_memcpy(&u, &h, 2);
  return u;
}
__device__ __forceinline__ float bf2f(ushort u) {
  uint32_t v = (uint32_t)u << 16;
  float f;
  __builtin_memcpy(&f, &v, 4);
  return f;
}
// async global->LDS, 16B per lane; linear dest, per-lane (gathered/swizzled)
// source address (m97/m173 pattern).
__device__ __forceinline__ void gload16(const void* g, void* l) {
  __builtin_amdgcn_global_load_lds(
      (const __attribute__((address_space(1))) u32*)g,
      (__attribute__((address_space(3))) u32*)l, 16, 0, 0);
}
// bf16 tile [rows][32 bf16]: stored linear, source chunk pre-XOR'd,
// read chunk XOR'd -> conflict-free (0 conflicts verified R3-R20).
__device__ __forceinline__ int swzread(int row, int q) {
  return row * 32 + ((q ^ ((row >> 1) & 3)) << 3);
}
// fp32 -> bf16 streaming body (NT loads), grid-strided over nblk blocks.
__device__ __forceinline__ void cvt_body(const float* __restrict__ src,
                                         ushort* __restrict__ dst,
                                         int blk, int nblk) {
  const int stride = nblk * 256;
  for (int i = blk * 256 + (int)threadIdx.x; i < NW8; i += stride) {
    f32x4 a = __builtin_nontemporal_load(((const f32x4*)src) + i * 2);
    f32x4 b = __builtin_nontemporal_load(((const f32x4*)src) + i * 2 + 1);
    uint4 t;
    t.x = pack2(a[0], a[1]); t.y = pack2(a[2], a[3]);
    t.z = pack2(b[0], b[1]); t.w = pack2(b[2], b[3]);
    ((uint4*)dst)[i] = t;
  }
}

// -- router (blocks 0..511) + piggyback cvt w1g AND cvt w1u (blocks 512+) --
__global__ __launch_bounds__(256) void router_kernel(
    const float* __restrict__ x, const float* __restrict__ gw,
    ushort* __restrict__ xb, int* __restrict__ topk_id,
    float* __restrict__ topk_w,
    const float* __restrict__ srcG, ushort* __restrict__ dstG,
    const float* __restrict__ srcU, ushort* __restrict__ dstU)
{
  if (blockIdx.x >= TTOK / 4 + NCVT) {
    cvt_body(srcU, dstU, blockIdx.x - (TTOK / 4 + NCVT), NCVT);
    return;
  }
  if (blockIdx.x >= TTOK / 4) {
    cvt_body(srcG, dstG, blockIdx.x - TTOK / 4, NCVT);
    return;
  }
  const int wid = threadIdx.x >> 6;
  const int lane = threadIdx.x & 63;
  const int t = blockIdx.x * 4 + wid;
  const float4* x4 = (const float4*)(x + (size_t)t * HDIM);
  const float4* gw4 = (const float4*)gw;
  float acc[NEXP];
#pragma unroll
  for (int e = 0; e < NEXP; ++e) acc[e] = 0.f;
#pragma unroll
  for (int i = 0; i < HDIM / 256; ++i) {
    const int idx = i * 64 + lane;
    float4 xv = x4[idx];
    uint2 xp;
    xp.x = pack2(xv.x, xv.y);
    xp.y = pack2(xv.z, xv.w);
    *(uint2*)(xb + (size_t)t * HDIM + idx * 4) = xp;
#pragma unroll
    for (int e = 0; e < NEXP; ++e) {
      float4 wv = gw4[e * (HDIM / 4) + idx];
      acc[e] += xv.x * wv.x + xv.y * wv.y + xv.z * wv.z + xv.w * wv.w;
    }
  }
#pragma unroll
  for (int e = 0; e < NEXP; ++e) {
#pragma unroll
    for (int off = 32; off >= 1; off >>= 1)
      acc[e] += __shfl_xor(acc[e], off);
  }
  if (lane == 0) {
    unsigned taken = 0;
    float vals[KSEL];
    int ids[KSEL];
#pragma unroll
    for (int k = 0; k < KSEL; ++k) {
      float bv = -3.4e38f; int bi = 0;
      for (int e = 0; e < NEXP; ++e)
        if (!((taken >> e) & 1u) && acc[e] > bv) { bv = acc[e]; bi = e; }
      taken |= 1u << bi; vals[k] = bv; ids[k] = bi;
    }
    float m = vals[0], s = 0.f, w[KSEL];
#pragma unroll
    for (int k = 0; k < KSEL; ++k) { w[k] = __expf(vals[k] - m); s += w[k]; }
    float is = 1.f / s;
#pragma unroll
    for (int k = 0; k < KSEL; ++k) {
      topk_id[t * KSEL + k] = ids[k];
      topk_w[t * KSEL + k] = w[k] * is;
    }
  }
}

// --- plan+scatter, single block: LDS histogram/cursors, no global atomics --
__global__ __launch_bounds__(1024) void plan_scatter_kernel(
    const int* __restrict__ topk_id, int* __restrict__ counts,
    int* __restrict__ offsets, int* __restrict__ nWA, int* __restrict__ nWB,
    int* __restrict__ wlA, int* __restrict__ wlB,
    int* __restrict__ rowTok, int* __restrict__ inv)
{
  __shared__ int cnt[NEXP], off[NEXP], cur[NEXP], tiles[NEXP], pre[NEXP];
  const int tid = threadIdx.x;
  if (tid < NEXP) { cnt[tid] = 0; cur[tid] = 0; }
  __syncthreads();
  for (int i = tid; i < TTOK * KSEL; i += 1024)
    atomicAdd(&cnt[topk_id[i]], 1);               // LDS atomics (fast)
  __syncthreads();
  if (tid == 0) {
    int s = 0, p = 0;
    for (int e = 0; e < NEXP; ++e) {
      off[e] = s; s += cnt[e];
      tiles[e] = (cnt[e] + 127) >> 7;
      pre[e] = p; p += tiles[e];
    }
    *nWA = p * NT1;
    *nWB = p * NTB;
  }
  __syncthreads();
  if (tid < NEXP) {
    counts[tid] = cnt[tid];
    offsets[tid] = off[tid];
    const int e = tid, T = tiles[e];
    int idx = pre[e] * NT1;
    for (int nt = 0; nt < NT1; ++nt)
      for (int mt = 0; mt < T; ++mt)
        wlA[idx++] = (e << 12) | (nt << 6) | mt;
  } else if (tid < 2 * NEXP) {
    const int e = tid - NEXP, T = tiles[e];
    int idx = pre[e] * NTB;
    for (int nt = 0; nt < NTB; ++nt)
      for (int mt = 0; mt < T; ++mt)
        wlB[idx++] = (e << 12) | (nt << 6) | mt;
  }
  for (int i = tid; i < TTOK * KSEL; i += 1024) {
    const int e = topk_id[i];
    const int pos = atomicAdd(&cur[e], 1);        // LDS atomic
    const int row = off[e] + pos;
    rowTok[row] = i >> 2;
    inv[i] = row;
  }
}

// -- gemm1 fused gate+up: each block computes 128 rows x (64 G-cols AND
//    64 U-cols) sharing one A tile; epilogue h = silu(g)*u -> hbuf (bf16),
//    straight-line (no branches). Blocks >= MAXB1: cvt(w2) piggyback.
//    Same per-block profile as R19: 16KB LDS/buffer, 16 MFMA/wave/K-step,
//    64 acc VGPRs, 4 gload16/thread/K-step. --------------------------------
__global__ __launch_bounds__(256) void gemm1_kernel(
    const ushort* __restrict__ xb,
    const ushort* __restrict__ wG, const ushort* __restrict__ wU,
    const int* __restrict__ rowTok, const int* __restrict__ counts,
    const int* __restrict__ offsets, const int* __restrict__ nW,
    const int* __restrict__ wl, ushort* __restrict__ hbuf,
    const float* __restrict__ cvsrc, ushort* __restrict__ cvdst)
{
  if (blockIdx.x >= MAXB1) {
    cvt_body(cvsrc, cvdst, blockIdx.x - MAXB1, NCVT);
    return;
  }
  const int nTot = *nW;
  const int L = (blockIdx.x & 7) * (MAXB1 / 8) + (blockIdx.x >> 3);
  if (L >= nTot) return;
  const int w = wl[L];
  const int e = w >> 12, nt = (w >> 6) & 63, mt = w & 63;
  const int n_e = counts[e], rowbase = offsets[e];

  __shared__ ushort As[2][128 * 32];
  __shared__ ushort Bg[2][64 * 32];
  __shared__ ushort Bu[2][64 * 32];

  const int tid = threadIdx.x;
  const int r0 = tid >> 2;            // 0..63
  const int ck = tid & 3;
  const int sch = (ck ^ ((r0 >> 1) & 3)) << 3;

  const int ar0 = mt * 128 + r0, ar1 = ar0 + 64;
  const int tok0 = rowTok[rowbase + (ar0 < n_e ? ar0 : n_e - 1)];
  const int tok1 = rowTok[rowbase + (ar1 < n_e ? ar1 : n_e - 1)];
  const ushort* pA0 = xb + (size_t)tok0 * HDIM + sch;
  const ushort* pA1 = xb + (size_t)tok1 * HDIM + sch;
  const size_t wbase = (size_t)e * IDIM * HDIM;
  const ushort* pBg = wG + wbase + (size_t)(nt * 64 + r0) * HDIM + sch;
  const ushort* pBu = wU + wbase + (size_t)(nt * 64 + r0) * HDIM + sch;

  const int lane = tid & 63;
  const int wid = tid >> 6;
  const int wr = (wid >> 1) << 6;     // wave rows 0/64
  const int wc = (wid & 1) << 5;      // wave cols 0/32 within the 64-col panel
  const int lr = lane & 15;
  const int q = lane >> 4;

  f32x4 accG[4][2], accU[4][2];
#pragma unroll
  for (int i = 0; i < 4; ++i)
#pragma unroll
    for (int j = 0; j < 2; ++j) {
      accG[i][j] = (f32x4){0.f, 0.f, 0.f, 0.f};
      accU[i][j] = (f32x4){0.f, 0.f, 0.f, 0.f};
    }

  auto STAGE = [&](int b) {
    gload16(pA0, &As[b][tid * 8]);
    gload16(pA1, &As[b][2048 + tid * 8]);
    gload16(pBg, &Bg[b][tid * 8]);
    gload16(pBu, &Bu[b][tid * 8]);
    pA0 += 32; pA1 += 32; pBg += 32; pBu += 32;
  };

  const int NTK = HDIM / 32;  // 64
  STAGE(0);
  __syncthreads();
  int buf = 0;
  for (int kt = 0; kt < NTK; ++kt) {
    if (kt + 1 < NTK) STAGE(buf ^ 1);
    bf16x8 af[4], bg[2], bu[2];
#pragma unroll
    for (int mi = 0; mi < 4; ++mi)
      af[mi] = *(const bf16x8*)&As[buf][swzread(wr + mi * 16 + lr, q)];
#pragma unroll
    for (int ni = 0; ni < 2; ++ni) {
      bg[ni] = *(const bf16x8*)&Bg[buf][swzread(wc + ni * 16 + lr, q)];
      bu[ni] = *(const bf16x8*)&Bu[buf][swzread(wc + ni * 16 + lr, q)];
    }
#pragma unroll
    for (int mi = 0; mi < 4; ++mi)
#pragma unroll
      for (int ni = 0; ni < 2; ++ni) {
        accG[mi][ni] = __builtin_amdgcn_mfma_f32_16x16x32_bf16(af[mi], bg[ni], accG[mi][ni], 0, 0, 0);
        accU[mi][ni] = __builtin_amdgcn_mfma_f32_16x16x32_bf16(af[mi], bu[ni], accU[mi][ni], 0, 0, 0);
      }
    __syncthreads();
    buf ^= 1;
  }

  // epilogue: h = silu(g) * u, straight-line, fp32 accs -> bf16 hbuf
#pragma unroll
  for (int mi = 0; mi < 4; ++mi) {
#pragma unroll
    for (int ni = 0; ni < 2; ++ni) {
      const int col = nt * 64 + wc + ni * 16 + lr;
#pragma unroll
      for (int r = 0; r < 4; ++r) {
        const int mrow = mt * 128 + wr + mi * 16 + q * 4 + r;
        if (mrow < n_e) {
          const float gv = accG[mi][ni][r];
          const float uv = accU[mi][ni][r];
          const float hv = (gv / (1.f + __expf(-gv))) * uv;
          hbuf[(size_t)(rowbase + mrow) * IDIM + col] = bf1(hv);
        }
      }
    }
  }
}

// ------- gemmB: po[rows][2048] = hbuf . w2^T  (pristine R15 body) -------
__global__ __launch_bounds__(256) void gemmB_kernel(
    const ushort* __restrict__ hb, const ushort* __restrict__ wb,
    const int* __restrict__ counts, const int* __restrict__ offsets,
    const int* __restrict__ nW, const int* __restrict__ wl,
    ushort* __restrict__ po)
{
  const int nTot = *nW;
  const int L = (blockIdx.x & 7) * (MAXBB / 8) + (blockIdx.x >> 3);
  if (L >= nTot) return;
  const int w = wl[L];
  const int e = w >> 12, nt = (w >> 6) & 63, mt = w & 63;
  const int n_e = counts[e], rowbase = offsets[e];

  __shared__ ushort As[2][128 * 32];
  __shared__ ushort Bs[2][128 * 32];

  const int tid = threadIdx.x;
  const int r0 = tid >> 2;
  const int ck = tid & 3;
  const int sch = (ck ^ ((r0 >> 1) & 3)) << 3;

  const int ar0 = mt * 128 + r0, ar1 = ar0 + 64;
  const int g0 = rowbase + (ar0 < n_e ? ar0 : n_e - 1);
  const int g1 = rowbase + (ar1 < n_e ? ar1 : n_e - 1);
  const ushort* pA0 = hb + (size_t)g0 * IDIM + sch;
  const ushort* pA1 = hb + (size_t)g1 * IDIM + sch;
  const size_t wbase = (size_t)e * HDIM * IDIM;
  const ushort* pB0 = wb + wbase + (size_t)(nt * 128 + r0) * IDIM + sch;
  const ushort* pB1 = wb + wbase + (size_t)(nt * 128 + r0 + 64) * IDIM + sch;

  const int lane = tid & 63;
  const int wid = tid >> 6;
  const int wr = (wid >> 1) << 6;
  const int wc = (wid & 1) << 6;
  const int lr = lane & 15;
  const int q = lane >> 4;

  f32x4 acc[4][4];
#pragma unroll
  for (int i = 0; i < 4; ++i)
#pragma unroll
    for (int j = 0; j < 4; ++j) acc[i][j] = (f32x4){0.f, 0.f, 0.f, 0.f};

  auto STAGE = [&](int b) {
    gload16(pA0, &As[b][tid * 8]);
    gload16(pA1, &As[b][2048 + tid * 8]);
    gload16(pB0, &Bs[b][tid * 8]);
    gload16(pB1, &Bs[b][2048 + tid * 8]);
    pA0 += 32; pA1 += 32; pB0 += 32; pB1 += 32;
  };

  const int NTK = IDIM / 32;  // 32
  STAGE(0);
  __syncthreads();
  int buf = 0;
  for (int kt = 0; kt < NTK; ++kt) {
    if (kt + 1 < NTK) STAGE(buf ^ 1);
    bf16x8 af[4], bfr[4];
#pragma unroll
    for (int mi = 0; mi < 4; ++mi)
      af[mi] = *(const bf16x8*)&As[buf][swzread(wr + mi * 16 + lr, q)];
#pragma unroll
    for (int ni = 0; ni < 4; ++ni)
      bfr[ni] = *(const bf16x8*)&Bs[buf][swzread(wc + ni * 16 + lr, q)];
#pragma unroll
    for (int mi = 0; mi < 4; ++mi)
#pragma unroll
      for (int ni = 0; ni < 4; ++ni)
        acc[mi][ni] = __builtin_amdgcn_mfma_f32_16x16x32_bf16(af[mi], bfr[ni], acc[mi][ni], 0, 0, 0);
    __syncthreads();
    buf ^= 1;
  }

#pragma unroll
  for (int mi = 0; mi < 4; ++mi) {
#pragma unroll
    for (int ni = 0; ni < 4; ++ni) {
      const int col = nt * 128 + wc + ni * 16 + lr;
#pragma unroll
      for (int r = 0; r < 4; ++r) {
        const int mrow = mt * 128 + wr + mi * 16 + q * 4 + r;
        if (mrow < n_e)
          po[(size_t)(rowbase + mrow) * HDIM + col] = bf1(acc[mi][ni][r]);
      }
    }
  }
}

// ---------------- combine: out[t] = sum_k w_k * po[row_k] -----------------
__global__ __launch_bounds__(256) void combine_kernel(
    const ushort* __restrict__ po, const int* __restrict__ inv,
    const float* __restrict__ tw, float* __restrict__ out)
{
  const int t = blockIdx.x;
  const int r0 = inv[t * 4 + 0], r1 = inv[t * 4 + 1];
  const int r2 = inv[t * 4 + 2], r3 = inv[t * 4 + 3];
  const float w0 = tw[t * 4 + 0], w1 = tw[t * 4 + 1];
  const float w2v = tw[t * 4 + 2], w3 = tw[t * 4 + 3];
  const int i = threadIdx.x;
  uint4 v0 = *(const uint4*)(po + (size_t)r0 * HDIM + i * 8);
  uint4 v1 = *(const uint4*)(po + (size_t)r1 * HDIM + i * 8);
  uint4 v2 = *(const uint4*)(po + (size_t)r2 * HDIM + i * 8);
  uint4 v3 = *(const uint4*)(po + (size_t)r3 * HDIM + i * 8);
  float o[8];
#pragma unroll
  for (int w = 0; w < 4; ++w) {
    const uint32_t a = (&v0.x)[w], b = (&v1.x)[w], c = (&v2.x)[w], d = (&v3.x)[w];
    o[w * 2 + 0] = w0 * __builtin_bit_cast(float, a << 16) +
                   w1 * __builtin_bit_cast(float, b << 16) +
                   w2v * __builtin_bit_cast(float, c << 16) +
                   w3 * __builtin_bit_cast(float, d << 16);
    o[w * 2 + 1] = w0 * __builtin_bit_cast(float, a & 0xffff0000u) +
                   w1 * __builtin_bit_cast(float, b & 0xffff0000u) +
                   w2v * __builtin_bit_cast(float, c & 0xffff0000u) +
                   w3 * __builtin_bit_cast(float, d & 0xffff0000u);
  }
  float4* o4 = (float4*)(out + (size_t)t * HDIM + i * 8);
  o4[0] = (float4){o[0], o[1], o[2], o[3]};
  o4[1] = (float4){o[4], o[5], o[6], o[7]};
}

extern "C" void kernel_launch(void* const* d_in, const int* in_sizes, int n_in,
                              void* d_out, int out_size, void* d_ws, size_t ws_size,
                              hipStream_t stream) {
  const float* x   = (const float*)d_in[0];
  const float* gw  = (const float*)d_in[1];
  const float* w1g = (const float*)d_in[2];
  const float* w1u = (const float*)d_in[3];
  const float* w2  = (const float*)d_in[4];
  float* out = (float*)d_out;

  char* ws = (char*)d_ws;
  // layout (bytes): xb 8MB @0; wbufG 64MB @8M; wbufU 64MB @72M;
  // wbuf2 64MB @136M; hbuf 16MB @200M; po 32MB @216M; idx @248M; ctrl.
  ushort* xb    = (ushort*)(ws + 0);
  ushort* wbufG = (ushort*)(ws + 8388608);
  ushort* wbufU = (ushort*)(ws + 75497472);
  ushort* wbuf2 = (ushort*)(ws + 142606336);
  ushort* hbuf  = (ushort*)(ws + 209715200);
  ushort* po    = (ushort*)(ws + 226492416);
  int*    tkid   = (int*)(ws + 260046848);
  float*  tkw    = (float*)(ws + 260046848 + 32768);
  int*    rowTok = (int*)(ws + 260046848 + 65536);
  int*    inv    = (int*)(ws + 260046848 + 98304);
  int*    ctrl   = (int*)(ws + 260177920);
  int* counts  = ctrl;           // 16
  int* offsets = ctrl + 32;      // 17
  int* nWA     = ctrl + 50;      // 1
  int* nWB     = ctrl + 51;      // 1
  int* wlA     = ctrl + 64;      // MAXB1 (1280)
  int* wlB     = ctrl + 64 + MAXB1;  // MAXBB (1280)

  // router + cvt(w1g) + cvt(w1u) overlap
  router_kernel<<<TTOK / 4 + 2 * NCVT, 256, 0, stream>>>(
      x, gw, xb, tkid, tkw, w1g, wbufG, w1u, wbufU);
  plan_scatter_kernel<<<1, 1024, 0, stream>>>(tkid, counts, offsets, nWA, nWB,
                                              wlA, wlB, rowTok, inv);
  // fused gate+up GEMM with silu epilogue -> hbuf; + cvt(w2) overlap
  gemm1_kernel<<<MAXB1 + NCVT, 256, 0, stream>>>(
      xb, wbufG, wbufU, rowTok, counts, offsets, nWA, wlA, hbuf,
      w2, wbuf2);
  // down pass (reads wbuf2)
  gemmB_kernel<<<MAXBB, 256, 0, stream>>>(hbuf, wbuf2, counts, offsets,
                                          nWB, wlB, po);
  combine_kernel<<<TTOK, 256, 0, stream>>>(po, inv, tkw, out);
}

// Round 22
// 312.599 us; speedup vs baseline: 1.1619x; 1.0438x over previous
//
#include <hip/hip_runtime.h>
#include <hip/hip_bf16.h>
#include <stdint.h>

#define NEXP 16
#define KSEL 4
#define HDIM 2048
#define IDIM 1024
#define TTOK 2048
#define NT1 16                   // gemm1 n-tiles (IDIM/64): 64 G + 64 U cols/block
#define NTB 16                   // gemmB n-tiles (HDIM/128)
#define MAXT1 47                 // max 256-row tiles: 8192/256 + 15
#define MAXB1 (MAXT1 * NT1)      // 752 (div by 8)
#define MAXTB 80                 // max 128-row tiles
#define MAXBB (MAXTB * NTB)      // 1280
#define NCVT 1024                // cvt blocks piggybacked on router (256 thr)
#define NCVT1 512                // cvt blocks piggybacked on gemm1 (512 thr)
#define NW8 ((NEXP * IDIM * HDIM) / 8)

typedef __attribute__((ext_vector_type(8))) short bf16x8;
typedef __attribute__((ext_vector_type(4))) float f32x4;
typedef unsigned int u32;

__device__ __forceinline__ uint32_t pack2(float a, float b) {
  __hip_bfloat162 h = __float22bfloat162_rn(float2{a, b});
  uint32_t u;
  __builtin_memcpy(&u, &h, 4);
  return u;
}
__device__ __forceinline__ ushort bf1(float a) {
  __hip_bfloat16 h = __float2bfloat16(a);
  ushort u;
  __builtin_memcpy(&u, &h, 2);
  return u;
}
// async global->LDS, 16B per lane; linear dest, per-lane (gathered/swizzled)
// source address (m97/m173 pattern).
__device__ __forceinline__ void gload16(const void* g, void* l) {
  __builtin_amdgcn_global_load_lds(
      (const __attribute__((address_space(1))) u32*)g,
      (__attribute__((address_space(3))) u32*)l, 16, 0, 0);
}
// bf16 tile [rows][32 bf16]: stored linear, source chunk pre-XOR'd,
// read chunk XOR'd -> conflict-free (0 conflicts verified R3-R21).
__device__ __forceinline__ int swzread(int row, int q) {
  return row * 32 + ((q ^ ((row >> 1) & 3)) << 3);
}
// fp32 -> bf16 streaming body (NT loads), explicit linear index/stride.
__device__ __forceinline__ void cvt_bodyN(const float* __restrict__ src,
                                          ushort* __restrict__ dst,
                                          int idx0, int stride) {
  for (int i = idx0; i < NW8; i += stride) {
    f32x4 a = __builtin_nontemporal_load(((const f32x4*)src) + i * 2);
    f32x4 b = __builtin_nontemporal_load(((const f32x4*)src) + i * 2 + 1);
    uint4 t;
    t.x = pack2(a[0], a[1]); t.y = pack2(a[2], a[3]);
    t.z = pack2(b[0], b[1]); t.w = pack2(b[2], b[3]);
    ((uint4*)dst)[i] = t;
  }
}

// -- router (blocks 0..511) + piggyback cvt w1g AND cvt w1u (blocks 512+) --
__global__ __launch_bounds__(256) void router_kernel(
    const float* __restrict__ x, const float* __restrict__ gw,
    ushort* __restrict__ xb, int* __restrict__ topk_id,
    float* __restrict__ topk_w,
    const float* __restrict__ srcG, ushort* __restrict__ dstG,
    const float* __restrict__ srcU, ushort* __restrict__ dstU)
{
  if (blockIdx.x >= TTOK / 4 + NCVT) {
    cvt_bodyN(srcU, dstU,
              (blockIdx.x - (TTOK / 4 + NCVT)) * 256 + threadIdx.x, NCVT * 256);
    return;
  }
  if (blockIdx.x >= TTOK / 4) {
    cvt_bodyN(srcG, dstG,
              (blockIdx.x - TTOK / 4) * 256 + threadIdx.x, NCVT * 256);
    return;
  }
  const int wid = threadIdx.x >> 6;
  const int lane = threadIdx.x & 63;
  const int t = blockIdx.x * 4 + wid;
  const float4* x4 = (const float4*)(x + (size_t)t * HDIM);
  const float4* gw4 = (const float4*)gw;
  float acc[NEXP];
#pragma unroll
  for (int e = 0; e < NEXP; ++e) acc[e] = 0.f;
#pragma unroll
  for (int i = 0; i < HDIM / 256; ++i) {
    const int idx = i * 64 + lane;
    float4 xv = x4[idx];
    uint2 xp;
    xp.x = pack2(xv.x, xv.y);
    xp.y = pack2(xv.z, xv.w);
    *(uint2*)(xb + (size_t)t * HDIM + idx * 4) = xp;
#pragma unroll
    for (int e = 0; e < NEXP; ++e) {
      float4 wv = gw4[e * (HDIM / 4) + idx];
      acc[e] += xv.x * wv.x + xv.y * wv.y + xv.z * wv.z + xv.w * wv.w;
    }
  }
#pragma unroll
  for (int e = 0; e < NEXP; ++e) {
#pragma unroll
    for (int off = 32; off >= 1; off >>= 1)
      acc[e] += __shfl_xor(acc[e], off);
  }
  if (lane == 0) {
    unsigned taken = 0;
    float vals[KSEL];
    int ids[KSEL];
#pragma unroll
    for (int k = 0; k < KSEL; ++k) {
      float bv = -3.4e38f; int bi = 0;
      for (int e = 0; e < NEXP; ++e)
        if (!((taken >> e) & 1u) && acc[e] > bv) { bv = acc[e]; bi = e; }
      taken |= 1u << bi; vals[k] = bv; ids[k] = bi;
    }
    float m = vals[0], s = 0.f, w[KSEL];
#pragma unroll
    for (int k = 0; k < KSEL; ++k) { w[k] = __expf(vals[k] - m); s += w[k]; }
    float is = 1.f / s;
#pragma unroll
    for (int k = 0; k < KSEL; ++k) {
      topk_id[t * KSEL + k] = ids[k];
      topk_w[t * KSEL + k] = w[k] * is;
    }
  }
}

// --- plan+scatter: LDS histogram/cursors; two tile granularities ----------
__global__ __launch_bounds__(1024) void plan_scatter_kernel(
    const int* __restrict__ topk_id, int* __restrict__ counts,
    int* __restrict__ offsets, int* __restrict__ nWA, int* __restrict__ nWB,
    int* __restrict__ wlA, int* __restrict__ wlB,
    int* __restrict__ rowTok, int* __restrict__ inv)
{
  __shared__ int cnt[NEXP], off[NEXP], cur[NEXP];
  __shared__ int t1[NEXP], p1[NEXP], tB[NEXP], pB[NEXP];
  const int tid = threadIdx.x;
  if (tid < NEXP) { cnt[tid] = 0; cur[tid] = 0; }
  __syncthreads();
  for (int i = tid; i < TTOK * KSEL; i += 1024)
    atomicAdd(&cnt[topk_id[i]], 1);               // LDS atomics
  __syncthreads();
  if (tid == 0) {
    int s = 0, a = 0, b = 0;
    for (int e = 0; e < NEXP; ++e) {
      off[e] = s; s += cnt[e];
      t1[e] = (cnt[e] + 255) >> 8;  p1[e] = a;  a += t1[e];
      tB[e] = (cnt[e] + 127) >> 7;  pB[e] = b;  b += tB[e];
    }
    *nWA = a * NT1;
    *nWB = b * NTB;
  }
  __syncthreads();
  if (tid < NEXP) {
    counts[tid] = cnt[tid];
    offsets[tid] = off[tid];
    const int e = tid, T = t1[e];
    int idx = p1[e] * NT1;
    for (int nt = 0; nt < NT1; ++nt)
      for (int mt = 0; mt < T; ++mt)
        wlA[idx++] = (e << 12) | (nt << 6) | mt;
  } else if (tid < 2 * NEXP) {
    const int e = tid - NEXP, T = tB[e];
    int idx = pB[e] * NTB;
    for (int nt = 0; nt < NTB; ++nt)
      for (int mt = 0; mt < T; ++mt)
        wlB[idx++] = (e << 12) | (nt << 6) | mt;
  }
  for (int i = tid; i < TTOK * KSEL; i += 1024) {
    const int e = topk_id[i];
    const int pos = atomicAdd(&cur[e], 1);        // LDS atomic
    const int row = off[e] + pos;
    rowTok[row] = i >> 2;
    inv[i] = row;
  }
}

// -- gemm1 fused gate+up, BM=256, 8 waves (512 thr):
//    per wave: 64 rows x (32 G-cols + 32 U-cols), 16 MFMA/K-step, 64 acc
//    VGPRs (identical to R21 wave profile). Weight-panel re-reads halve.
//    Staging: 8 waves x {2x A, 1x B} gload16/lane, linear dest, swz source.
//    Blocks >= MAXB1: cvt(w2) piggyback. ----------------------------------
__global__ __launch_bounds__(512) void gemm1_kernel(
    const ushort* __restrict__ xb,
    const ushort* __restrict__ wG, const ushort* __restrict__ wU,
    const int* __restrict__ rowTok, const int* __restrict__ counts,
    const int* __restrict__ offsets, const int* __restrict__ nW,
    const int* __restrict__ wl, ushort* __restrict__ hbuf,
    const float* __restrict__ cvsrc, ushort* __restrict__ cvdst)
{
  if (blockIdx.x >= MAXB1) {
    cvt_bodyN(cvsrc, cvdst,
              (blockIdx.x - MAXB1) * 512 + threadIdx.x, NCVT1 * 512);
    return;
  }
  const int nTot = *nW;
  const int L = (blockIdx.x & 7) * (MAXB1 / 8) + (blockIdx.x >> 3);
  if (L >= nTot) return;
  const int w = wl[L];
  const int e = w >> 12, nt = (w >> 6) & 63, mt = w & 63;
  const int n_e = counts[e], rowbase = offsets[e];

  __shared__ ushort As[2][256 * 32];   // 16 KB each
  __shared__ ushort Bg[2][64 * 32];    // 4 KB each
  __shared__ ushort Bu[2][64 * 32];    // 4 KB each

  const int tid = threadIdx.x;
  const int lane = tid & 63;
  const int wid = tid >> 6;            // 0..7

  // ---- staging addresses ----
  // A: wave wid stages local rows [wid*32, wid*32+32): two 1KB instrs.
  const int lr4 = lane >> 2;           // 0..15
  const int ckA = lane & 3;
  const int arl0 = wid * 32 + lr4;         // j=0 local row
  const int arl1 = wid * 32 + 16 + lr4;    // j=1 local row
  const int schA0 = (ckA ^ ((arl0 >> 1) & 3)) << 3;
  const int schA1 = (ckA ^ ((arl1 >> 1) & 3)) << 3;
  const int ag0 = mt * 256 + arl0, ag1 = mt * 256 + arl1;
  const int tok0 = rowTok[rowbase + (ag0 < n_e ? ag0 : n_e - 1)];
  const int tok1 = rowTok[rowbase + (ag1 < n_e ? ag1 : n_e - 1)];
  const ushort* pA0 = xb + (size_t)tok0 * HDIM + schA0;
  const ushort* pA1 = xb + (size_t)tok1 * HDIM + schA1;
  // B: waves 0-3 -> Bg rows [wid*16,+16); waves 4-7 -> Bu rows [(wid-4)*16,+16)
  const int brl = (wid & 3) * 16 + lr4;    // local B row 0..63
  const int schB = (ckA ^ ((brl >> 1) & 3)) << 3;
  const size_t wbase = (size_t)e * IDIM * HDIM;
  const ushort* pB = ((wid < 4) ? wG : wU) + wbase +
                     (size_t)(nt * 64 + brl) * HDIM + schB;

  // ---- compute geometry: 8 waves = 4 Mgrp x 2 Ngrp ----
  const int wr = (wid >> 1) << 6;      // 0/64/128/192
  const int wc = (wid & 1) << 5;       // 0/32
  const int lr = lane & 15;
  const int q = lane >> 4;

  f32x4 accG[4][2], accU[4][2];
#pragma unroll
  for (int i = 0; i < 4; ++i)
#pragma unroll
    for (int j = 0; j < 2; ++j) {
      accG[i][j] = (f32x4){0.f, 0.f, 0.f, 0.f};
      accU[i][j] = (f32x4){0.f, 0.f, 0.f, 0.f};
    }

  auto STAGE = [&](int b) {
    gload16(pA0, &As[b][wid * 1024 + lane * 8]);
    gload16(pA1, &As[b][wid * 1024 + 512 + lane * 8]);
    if (wid < 4) gload16(pB, &Bg[b][wid * 512 + lane * 8]);
    else         gload16(pB, &Bu[b][(wid - 4) * 512 + lane * 8]);
    pA0 += 32; pA1 += 32; pB += 32;
  };

  const int NTK = HDIM / 32;  // 64
  STAGE(0);
  __syncthreads();
  int buf = 0;
  for (int kt = 0; kt < NTK; ++kt) {
    if (kt + 1 < NTK) STAGE(buf ^ 1);
    bf16x8 af[4], bg[2], bu[2];
#pragma unroll
    for (int mi = 0; mi < 4; ++mi)
      af[mi] = *(const bf16x8*)&As[buf][swzread(wr + mi * 16 + lr, q)];
#pragma unroll
    for (int ni = 0; ni < 2; ++ni) {
      bg[ni] = *(const bf16x8*)&Bg[buf][swzread(wc + ni * 16 + lr, q)];
      bu[ni] = *(const bf16x8*)&Bu[buf][swzread(wc + ni * 16 + lr, q)];
    }
#pragma unroll
    for (int mi = 0; mi < 4; ++mi)
#pragma unroll
      for (int ni = 0; ni < 2; ++ni) {
        accG[mi][ni] = __builtin_amdgcn_mfma_f32_16x16x32_bf16(af[mi], bg[ni], accG[mi][ni], 0, 0, 0);
        accU[mi][ni] = __builtin_amdgcn_mfma_f32_16x16x32_bf16(af[mi], bu[ni], accU[mi][ni], 0, 0, 0);
      }
    __syncthreads();
    buf ^= 1;
  }

  // epilogue: h = silu(g) * u (straight-line)
#pragma unroll
  for (int mi = 0; mi < 4; ++mi) {
#pragma unroll
    for (int ni = 0; ni < 2; ++ni) {
      const int col = nt * 64 + wc + ni * 16 + lr;
#pragma unroll
      for (int r = 0; r < 4; ++r) {
        const int mrow = mt * 256 + wr + mi * 16 + q * 4 + r;
        if (mrow < n_e) {
          const float gv = accG[mi][ni][r];
          const float uv = accU[mi][ni][r];
          const float hv = (gv / (1.f + __expf(-gv))) * uv;
          hbuf[(size_t)(rowbase + mrow) * IDIM + col] = bf1(hv);
        }
      }
    }
  }
}

// ------- gemmB: po[rows][2048] = hbuf . w2^T  (pristine R15 body) -------
__global__ __launch_bounds__(256) void gemmB_kernel(
    const ushort* __restrict__ hb, const ushort* __restrict__ wb,
    const int* __restrict__ counts, const int* __restrict__ offsets,
    const int* __restrict__ nW, const int* __restrict__ wl,
    ushort* __restrict__ po)
{
  const int nTot = *nW;
  const int L = (blockIdx.x & 7) * (MAXBB / 8) + (blockIdx.x >> 3);
  if (L >= nTot) return;
  const int w = wl[L];
  const int e = w >> 12, nt = (w >> 6) & 63, mt = w & 63;
  const int n_e = counts[e], rowbase = offsets[e];

  __shared__ ushort As[2][128 * 32];
  __shared__ ushort Bs[2][128 * 32];

  const int tid = threadIdx.x;
  const int r0 = tid >> 2;
  const int ck = tid & 3;
  const int sch = (ck ^ ((r0 >> 1) & 3)) << 3;

  const int ar0 = mt * 128 + r0, ar1 = ar0 + 64;
  const int g0 = rowbase + (ar0 < n_e ? ar0 : n_e - 1);
  const int g1 = rowbase + (ar1 < n_e ? ar1 : n_e - 1);
  const ushort* pA0 = hb + (size_t)g0 * IDIM + sch;
  const ushort* pA1 = hb + (size_t)g1 * IDIM + sch;
  const size_t wbase = (size_t)e * HDIM * IDIM;
  const ushort* pB0 = wb + wbase + (size_t)(nt * 128 + r0) * IDIM + sch;
  const ushort* pB1 = wb + wbase + (size_t)(nt * 128 + r0 + 64) * IDIM + sch;

  const int lane = tid & 63;
  const int wid = tid >> 6;
  const int wr = (wid >> 1) << 6;
  const int wc = (wid & 1) << 6;
  const int lr = lane & 15;
  const int q = lane >> 4;

  f32x4 acc[4][4];
#pragma unroll
  for (int i = 0; i < 4; ++i)
#pragma unroll
    for (int j = 0; j < 4; ++j) acc[i][j] = (f32x4){0.f, 0.f, 0.f, 0.f};

  auto STAGE = [&](int b) {
    gload16(pA0, &As[b][tid * 8]);
    gload16(pA1, &As[b][2048 + tid * 8]);
    gload16(pB0, &Bs[b][tid * 8]);
    gload16(pB1, &Bs[b][2048 + tid * 8]);
    pA0 += 32; pA1 += 32; pB0 += 32; pB1 += 32;
  };

  const int NTK = IDIM / 32;  // 32
  STAGE(0);
  __syncthreads();
  int buf = 0;
  for (int kt = 0; kt < NTK; ++kt) {
    if (kt + 1 < NTK) STAGE(buf ^ 1);
    bf16x8 af[4], bfr[4];
#pragma unroll
    for (int mi = 0; mi < 4; ++mi)
      af[mi] = *(const bf16x8*)&As[buf][swzread(wr + mi * 16 + lr, q)];
#pragma unroll
    for (int ni = 0; ni < 4; ++ni)
      bfr[ni] = *(const bf16x8*)&Bs[buf][swzread(wc + ni * 16 + lr, q)];
#pragma unroll
    for (int mi = 0; mi < 4; ++mi)
#pragma unroll
      for (int ni = 0; ni < 4; ++ni)
        acc[mi][ni] = __builtin_amdgcn_mfma_f32_16x16x32_bf16(af[mi], bfr[ni], acc[mi][ni], 0, 0, 0);
    __syncthreads();
    buf ^= 1;
  }

#pragma unroll
  for (int mi = 0; mi < 4; ++mi) {
#pragma unroll
    for (int ni = 0; ni < 4; ++ni) {
      const int col = nt * 128 + wc + ni * 16 + lr;
#pragma unroll
      for (int r = 0; r < 4; ++r) {
        const int mrow = mt * 128 + wr + mi * 16 + q * 4 + r;
        if (mrow < n_e)
          po[(size_t)(rowbase + mrow) * HDIM + col] = bf1(acc[mi][ni][r]);
      }
    }
  }
}

// ---------------- combine: out[t] = sum_k w_k * po[row_k] -----------------
__global__ __launch_bounds__(256) void combine_kernel(
    const ushort* __restrict__ po, const int* __restrict__ inv,
    const float* __restrict__ tw, float* __restrict__ out)
{
  const int t = blockIdx.x;
  const int r0 = inv[t * 4 + 0], r1 = inv[t * 4 + 1];
  const int r2 = inv[t * 4 + 2], r3 = inv[t * 4 + 3];
  const float w0 = tw[t * 4 + 0], w1 = tw[t * 4 + 1];
  const float w2v = tw[t * 4 + 2], w3 = tw[t * 4 + 3];
  const int i = threadIdx.x;
  uint4 v0 = *(const uint4*)(po + (size_t)r0 * HDIM + i * 8);
  uint4 v1 = *(const uint4*)(po + (size_t)r1 * HDIM + i * 8);
  uint4 v2 = *(const uint4*)(po + (size_t)r2 * HDIM + i * 8);
  uint4 v3 = *(const uint4*)(po + (size_t)r3 * HDIM + i * 8);
  float o[8];
#pragma unroll
  for (int w = 0; w < 4; ++w) {
    const uint32_t a = (&v0.x)[w], b = (&v1.x)[w], c = (&v2.x)[w], d = (&v3.x)[w];
    o[w * 2 + 0] = w0 * __builtin_bit_cast(float, a << 16) +
                   w1 * __builtin_bit_cast(float, b << 16) +
                   w2v * __builtin_bit_cast(float, c << 16) +
                   w3 * __builtin_bit_cast(float, d << 16);
    o[w * 2 + 1] = w0 * __builtin_bit_cast(float, a & 0xffff0000u) +
                   w1 * __builtin_bit_cast(float, b & 0xffff0000u) +
                   w2v * __builtin_bit_cast(float, c & 0xffff0000u) +
                   w3 * __builtin_bit_cast(float, d & 0xffff0000u);
  }
  float4* o4 = (float4*)(out + (size_t)t * HDIM + i * 8);
  o4[0] = (float4){o[0], o[1], o[2], o[3]};
  o4[1] = (float4){o[4], o[5], o[6], o[7]};
}

extern "C" void kernel_launch(void* const* d_in, const int* in_sizes, int n_in,
                              void* d_out, int out_size, void* d_ws, size_t ws_size,
                              hipStream_t stream) {
  const float* x   = (const float*)d_in[0];
  const float* gw  = (const float*)d_in[1];
  const float* w1g = (const float*)d_in[2];
  const float* w1u = (const float*)d_in[3];
  const float* w2  = (const float*)d_in[4];
  float* out = (float*)d_out;

  char* ws = (char*)d_ws;
  // layout (bytes): xb 8MB @0; wbufG 64MB @8M; wbufU 64MB @72M;
  // wbuf2 64MB @136M; hbuf 16MB @200M; po 32MB @216M; idx @248M; ctrl.
  ushort* xb    = (ushort*)(ws + 0);
  ushort* wbufG = (ushort*)(ws + 8388608);
  ushort* wbufU = (ushort*)(ws + 75497472);
  ushort* wbuf2 = (ushort*)(ws + 142606336);
  ushort* hbuf  = (ushort*)(ws + 209715200);
  ushort* po    = (ushort*)(ws + 226492416);
  int*    tkid   = (int*)(ws + 260046848);
  float*  tkw    = (float*)(ws + 260046848 + 32768);
  int*    rowTok = (int*)(ws + 260046848 + 65536);
  int*    inv    = (int*)(ws + 260046848 + 98304);
  int*    ctrl   = (int*)(ws + 260177920);
  int* counts  = ctrl;           // 16
  int* offsets = ctrl + 32;      // 17
  int* nWA     = ctrl + 50;      // 1
  int* nWB     = ctrl + 51;      // 1
  int* wlA     = ctrl + 64;      // MAXB1 (752)
  int* wlB     = ctrl + 64 + MAXB1;  // MAXBB (1280)

  // router + cvt(w1g) + cvt(w1u) overlap
  router_kernel<<<TTOK / 4 + 2 * NCVT, 256, 0, stream>>>(
      x, gw, xb, tkid, tkw, w1g, wbufG, w1u, wbufU);
  plan_scatter_kernel<<<1, 1024, 0, stream>>>(tkid, counts, offsets, nWA, nWB,
                                              wlA, wlB, rowTok, inv);
  // fused gate+up GEMM (BM=256, 8 waves) + silu epilogue; + cvt(w2) overlap
  gemm1_kernel<<<MAXB1 + NCVT1, 512, 0, stream>>>(
      xb, wbufG, wbufU, rowTok, counts, offsets, nWA, wlA, hbuf,
      w2, wbuf2);
  // down pass (reads wbuf2)
  gemmB_kernel<<<MAXBB, 256, 0, stream>>>(hbuf, wbuf2, counts, offsets,
                                          nWB, wlB, po);
  combine_kernel<<<TTOK, 256, 0, stream>>>(po, inv, tkw, out);
}

// Round 23
// 310.170 us; speedup vs baseline: 1.1710x; 1.0078x over previous
//
#include <hip/hip_runtime.h>
#include <hip/hip_bf16.h>
#include <stdint.h>

#define NEXP 16
#define KSEL 4
#define HDIM 2048
#define IDIM 1024
#define TTOK 2048
#define NT1 16                   // gemm1 n-tiles (IDIM/64): 64 G + 64 U cols/block
#define NTB 16                   // gemmB n-tiles (HDIM/128)
#define MAXT1 47                 // max 256-row tiles: 8192/256 + 15
#define MAXB1 (MAXT1 * NT1)      // 752 (div by 8)
#define MAXBB (MAXT1 * NTB)      // 752 (256-row tiles for gemmB too)
#define NCVT 1024                // cvt blocks piggybacked on router (256 thr)
#define NCVT1 512                // cvt blocks piggybacked on gemm1 (512 thr)
#define NW8 ((NEXP * IDIM * HDIM) / 8)

typedef __attribute__((ext_vector_type(8))) short bf16x8;
typedef __attribute__((ext_vector_type(4))) float f32x4;
typedef unsigned int u32;

__device__ __forceinline__ uint32_t pack2(float a, float b) {
  __hip_bfloat162 h = __float22bfloat162_rn(float2{a, b});
  uint32_t u;
  __builtin_memcpy(&u, &h, 4);
  return u;
}
__device__ __forceinline__ ushort bf1(float a) {
  __hip_bfloat16 h = __float2bfloat16(a);
  ushort u;
  __builtin_memcpy(&u, &h, 2);
  return u;
}
// async global->LDS, 16B per lane; linear dest, per-lane (gathered/swizzled)
// source address (m97/m173 pattern).
__device__ __forceinline__ void gload16(const void* g, void* l) {
  __builtin_amdgcn_global_load_lds(
      (const __attribute__((address_space(1))) u32*)g,
      (__attribute__((address_space(3))) u32*)l, 16, 0, 0);
}
// bf16 tile [rows][32 bf16]: stored linear, source chunk pre-XOR'd,
// read chunk XOR'd -> conflict-free (0 conflicts verified R3-R22).
__device__ __forceinline__ int swzread(int row, int q) {
  return row * 32 + ((q ^ ((row >> 1) & 3)) << 3);
}
// fp32 -> bf16 streaming body (NT loads), explicit linear index/stride.
__device__ __forceinline__ void cvt_bodyN(const float* __restrict__ src,
                                          ushort* __restrict__ dst,
                                          int idx0, int stride) {
  for (int i = idx0; i < NW8; i += stride) {
    f32x4 a = __builtin_nontemporal_load(((const f32x4*)src) + i * 2);
    f32x4 b = __builtin_nontemporal_load(((const f32x4*)src) + i * 2 + 1);
    uint4 t;
    t.x = pack2(a[0], a[1]); t.y = pack2(a[2], a[3]);
    t.z = pack2(b[0], b[1]); t.w = pack2(b[2], b[3]);
    ((uint4*)dst)[i] = t;
  }
}

// -- router (blocks 0..511) + piggyback cvt w1g AND cvt w1u (blocks 512+) --
__global__ __launch_bounds__(256) void router_kernel(
    const float* __restrict__ x, const float* __restrict__ gw,
    ushort* __restrict__ xb, int* __restrict__ topk_id,
    float* __restrict__ topk_w,
    const float* __restrict__ srcG, ushort* __restrict__ dstG,
    const float* __restrict__ srcU, ushort* __restrict__ dstU)
{
  if (blockIdx.x >= TTOK / 4 + NCVT) {
    cvt_bodyN(srcU, dstU,
              (blockIdx.x - (TTOK / 4 + NCVT)) * 256 + threadIdx.x, NCVT * 256);
    return;
  }
  if (blockIdx.x >= TTOK / 4) {
    cvt_bodyN(srcG, dstG,
              (blockIdx.x - TTOK / 4) * 256 + threadIdx.x, NCVT * 256);
    return;
  }
  const int wid = threadIdx.x >> 6;
  const int lane = threadIdx.x & 63;
  const int t = blockIdx.x * 4 + wid;
  const float4* x4 = (const float4*)(x + (size_t)t * HDIM);
  const float4* gw4 = (const float4*)gw;
  float acc[NEXP];
#pragma unroll
  for (int e = 0; e < NEXP; ++e) acc[e] = 0.f;
#pragma unroll
  for (int i = 0; i < HDIM / 256; ++i) {
    const int idx = i * 64 + lane;
    float4 xv = x4[idx];
    uint2 xp;
    xp.x = pack2(xv.x, xv.y);
    xp.y = pack2(xv.z, xv.w);
    *(uint2*)(xb + (size_t)t * HDIM + idx * 4) = xp;
#pragma unroll
    for (int e = 0; e < NEXP; ++e) {
      float4 wv = gw4[e * (HDIM / 4) + idx];
      acc[e] += xv.x * wv.x + xv.y * wv.y + xv.z * wv.z + xv.w * wv.w;
    }
  }
#pragma unroll
  for (int e = 0; e < NEXP; ++e) {
#pragma unroll
    for (int off = 32; off >= 1; off >>= 1)
      acc[e] += __shfl_xor(acc[e], off);
  }
  if (lane == 0) {
    unsigned taken = 0;
    float vals[KSEL];
    int ids[KSEL];
#pragma unroll
    for (int k = 0; k < KSEL; ++k) {
      float bv = -3.4e38f; int bi = 0;
      for (int e = 0; e < NEXP; ++e)
        if (!((taken >> e) & 1u) && acc[e] > bv) { bv = acc[e]; bi = e; }
      taken |= 1u << bi; vals[k] = bv; ids[k] = bi;
    }
    float m = vals[0], s = 0.f, w[KSEL];
#pragma unroll
    for (int k = 0; k < KSEL; ++k) { w[k] = __expf(vals[k] - m); s += w[k]; }
    float is = 1.f / s;
#pragma unroll
    for (int k = 0; k < KSEL; ++k) {
      topk_id[t * KSEL + k] = ids[k];
      topk_w[t * KSEL + k] = w[k] * is;
    }
  }
}

// --- plan+scatter: LDS histogram/cursors; 256-row tiles for both GEMMs ----
__global__ __launch_bounds__(1024) void plan_scatter_kernel(
    const int* __restrict__ topk_id, int* __restrict__ counts,
    int* __restrict__ offsets, int* __restrict__ nWA, int* __restrict__ nWB,
    int* __restrict__ wlA, int* __restrict__ wlB,
    int* __restrict__ rowTok, int* __restrict__ inv)
{
  __shared__ int cnt[NEXP], off[NEXP], cur[NEXP];
  __shared__ int t1[NEXP], p1[NEXP];
  const int tid = threadIdx.x;
  if (tid < NEXP) { cnt[tid] = 0; cur[tid] = 0; }
  __syncthreads();
  for (int i = tid; i < TTOK * KSEL; i += 1024)
    atomicAdd(&cnt[topk_id[i]], 1);               // LDS atomics
  __syncthreads();
  if (tid == 0) {
    int s = 0, a = 0;
    for (int e = 0; e < NEXP; ++e) {
      off[e] = s; s += cnt[e];
      t1[e] = (cnt[e] + 255) >> 8;  p1[e] = a;  a += t1[e];
    }
    *nWA = a * NT1;
    *nWB = a * NTB;
  }
  __syncthreads();
  if (tid < NEXP) {
    counts[tid] = cnt[tid];
    offsets[tid] = off[tid];
    const int e = tid, T = t1[e];
    int idx = p1[e] * NT1;
    for (int nt = 0; nt < NT1; ++nt)
      for (int mt = 0; mt < T; ++mt)
        wlA[idx++] = (e << 12) | (nt << 6) | mt;
  } else if (tid < 2 * NEXP) {
    const int e = tid - NEXP, T = t1[e];
    int idx = p1[e] * NTB;
    for (int nt = 0; nt < NTB; ++nt)
      for (int mt = 0; mt < T; ++mt)
        wlB[idx++] = (e << 12) | (nt << 6) | mt;
  }
  for (int i = tid; i < TTOK * KSEL; i += 1024) {
    const int e = topk_id[i];
    const int pos = atomicAdd(&cur[e], 1);        // LDS atomic
    const int row = off[e] + pos;
    rowTok[row] = i >> 2;
    inv[i] = row;
  }
}

// -- gemm1 fused gate+up, BM=256, 8 waves (512 thr) — R22 winner, unchanged.
__global__ __launch_bounds__(512) void gemm1_kernel(
    const ushort* __restrict__ xb,
    const ushort* __restrict__ wG, const ushort* __restrict__ wU,
    const int* __restrict__ rowTok, const int* __restrict__ counts,
    const int* __restrict__ offsets, const int* __restrict__ nW,
    const int* __restrict__ wl, ushort* __restrict__ hbuf,
    const float* __restrict__ cvsrc, ushort* __restrict__ cvdst)
{
  if (blockIdx.x >= MAXB1) {
    cvt_bodyN(cvsrc, cvdst,
              (blockIdx.x - MAXB1) * 512 + threadIdx.x, NCVT1 * 512);
    return;
  }
  const int nTot = *nW;
  const int L = (blockIdx.x & 7) * (MAXB1 / 8) + (blockIdx.x >> 3);
  if (L >= nTot) return;
  const int w = wl[L];
  const int e = w >> 12, nt = (w >> 6) & 63, mt = w & 63;
  const int n_e = counts[e], rowbase = offsets[e];

  __shared__ ushort As[2][256 * 32];
  __shared__ ushort Bg[2][64 * 32];
  __shared__ ushort Bu[2][64 * 32];

  const int tid = threadIdx.x;
  const int lane = tid & 63;
  const int wid = tid >> 6;

  const int lr4 = lane >> 2;
  const int ckA = lane & 3;
  const int arl0 = wid * 32 + lr4;
  const int arl1 = wid * 32 + 16 + lr4;
  const int schA0 = (ckA ^ ((arl0 >> 1) & 3)) << 3;
  const int schA1 = (ckA ^ ((arl1 >> 1) & 3)) << 3;
  const int ag0 = mt * 256 + arl0, ag1 = mt * 256 + arl1;
  const int tok0 = rowTok[rowbase + (ag0 < n_e ? ag0 : n_e - 1)];
  const int tok1 = rowTok[rowbase + (ag1 < n_e ? ag1 : n_e - 1)];
  const ushort* pA0 = xb + (size_t)tok0 * HDIM + schA0;
  const ushort* pA1 = xb + (size_t)tok1 * HDIM + schA1;
  const int brl = (wid & 3) * 16 + lr4;
  const int schB = (ckA ^ ((brl >> 1) & 3)) << 3;
  const size_t wbase = (size_t)e * IDIM * HDIM;
  const ushort* pB = ((wid < 4) ? wG : wU) + wbase +
                     (size_t)(nt * 64 + brl) * HDIM + schB;

  const int wr = (wid >> 1) << 6;
  const int wc = (wid & 1) << 5;
  const int lr = lane & 15;
  const int q = lane >> 4;

  f32x4 accG[4][2], accU[4][2];
#pragma unroll
  for (int i = 0; i < 4; ++i)
#pragma unroll
    for (int j = 0; j < 2; ++j) {
      accG[i][j] = (f32x4){0.f, 0.f, 0.f, 0.f};
      accU[i][j] = (f32x4){0.f, 0.f, 0.f, 0.f};
    }

  auto STAGE = [&](int b) {
    gload16(pA0, &As[b][wid * 1024 + lane * 8]);
    gload16(pA1, &As[b][wid * 1024 + 512 + lane * 8]);
    if (wid < 4) gload16(pB, &Bg[b][wid * 512 + lane * 8]);
    else         gload16(pB, &Bu[b][(wid - 4) * 512 + lane * 8]);
    pA0 += 32; pA1 += 32; pB += 32;
  };

  const int NTK = HDIM / 32;  // 64
  STAGE(0);
  __syncthreads();
  int buf = 0;
  for (int kt = 0; kt < NTK; ++kt) {
    if (kt + 1 < NTK) STAGE(buf ^ 1);
    bf16x8 af[4], bg[2], bu[2];
#pragma unroll
    for (int mi = 0; mi < 4; ++mi)
      af[mi] = *(const bf16x8*)&As[buf][swzread(wr + mi * 16 + lr, q)];
#pragma unroll
    for (int ni = 0; ni < 2; ++ni) {
      bg[ni] = *(const bf16x8*)&Bg[buf][swzread(wc + ni * 16 + lr, q)];
      bu[ni] = *(const bf16x8*)&Bu[buf][swzread(wc + ni * 16 + lr, q)];
    }
#pragma unroll
    for (int mi = 0; mi < 4; ++mi)
#pragma unroll
      for (int ni = 0; ni < 2; ++ni) {
        accG[mi][ni] = __builtin_amdgcn_mfma_f32_16x16x32_bf16(af[mi], bg[ni], accG[mi][ni], 0, 0, 0);
        accU[mi][ni] = __builtin_amdgcn_mfma_f32_16x16x32_bf16(af[mi], bu[ni], accU[mi][ni], 0, 0, 0);
      }
    __syncthreads();
    buf ^= 1;
  }

#pragma unroll
  for (int mi = 0; mi < 4; ++mi) {
#pragma unroll
    for (int ni = 0; ni < 2; ++ni) {
      const int col = nt * 64 + wc + ni * 16 + lr;
#pragma unroll
      for (int r = 0; r < 4; ++r) {
        const int mrow = mt * 256 + wr + mi * 16 + q * 4 + r;
        if (mrow < n_e) {
          const float gv = accG[mi][ni][r];
          const float uv = accU[mi][ni][r];
          const float hv = (gv / (1.f + __expf(-gv))) * uv;
          hbuf[(size_t)(rowbase + mrow) * IDIM + col] = bf1(hv);
        }
      }
    }
  }
}

// -- gemmB BM=256, 8 waves (512 thr): per wave 64 rows x 64 cols, acc[4][4],
//    16 MFMA/K-step; staging 3 gload16/lane; LDS 48KB. Same transform as
//    gemm1 R22 (verified). --------------------------------------------------
__global__ __launch_bounds__(512) void gemmB_kernel(
    const ushort* __restrict__ hb, const ushort* __restrict__ wb,
    const int* __restrict__ counts, const int* __restrict__ offsets,
    const int* __restrict__ nW, const int* __restrict__ wl,
    ushort* __restrict__ po)
{
  const int nTot = *nW;
  const int L = (blockIdx.x & 7) * (MAXBB / 8) + (blockIdx.x >> 3);
  if (L >= nTot) return;
  const int w = wl[L];
  const int e = w >> 12, nt = (w >> 6) & 63, mt = w & 63;
  const int n_e = counts[e], rowbase = offsets[e];

  __shared__ ushort As[2][256 * 32];   // 16 KB each
  __shared__ ushort Bs[2][128 * 32];   // 8 KB each

  const int tid = threadIdx.x;
  const int lane = tid & 63;
  const int wid = tid >> 6;

  const int lr4 = lane >> 2;
  const int ckA = lane & 3;
  const int arl0 = wid * 32 + lr4;
  const int arl1 = wid * 32 + 16 + lr4;
  const int schA0 = (ckA ^ ((arl0 >> 1) & 3)) << 3;
  const int schA1 = (ckA ^ ((arl1 >> 1) & 3)) << 3;
  const int ag0 = mt * 256 + arl0, ag1 = mt * 256 + arl1;
  const int g0 = rowbase + (ag0 < n_e ? ag0 : n_e - 1);
  const int g1 = rowbase + (ag1 < n_e ? ag1 : n_e - 1);
  const ushort* pA0 = hb + (size_t)g0 * IDIM + schA0;
  const ushort* pA1 = hb + (size_t)g1 * IDIM + schA1;
  const int brl = wid * 16 + lr4;      // 0..127
  const int schB = (ckA ^ ((brl >> 1) & 3)) << 3;
  const size_t wbase = (size_t)e * HDIM * IDIM;
  const ushort* pB = wb + wbase + (size_t)(nt * 128 + brl) * IDIM + schB;

  const int wr = (wid >> 1) << 6;      // 0/64/128/192
  const int wc = (wid & 1) << 6;       // 0/64
  const int lr = lane & 15;
  const int q = lane >> 4;

  f32x4 acc[4][4];
#pragma unroll
  for (int i = 0; i < 4; ++i)
#pragma unroll
    for (int j = 0; j < 4; ++j) acc[i][j] = (f32x4){0.f, 0.f, 0.f, 0.f};

  auto STAGE = [&](int b) {
    gload16(pA0, &As[b][wid * 1024 + lane * 8]);
    gload16(pA1, &As[b][wid * 1024 + 512 + lane * 8]);
    gload16(pB, &Bs[b][wid * 512 + lane * 8]);
    pA0 += 32; pA1 += 32; pB += 32;
  };

  const int NTK = IDIM / 32;  // 32
  STAGE(0);
  __syncthreads();
  int buf = 0;
  for (int kt = 0; kt < NTK; ++kt) {
    if (kt + 1 < NTK) STAGE(buf ^ 1);
    bf16x8 af[4], bfr[4];
#pragma unroll
    for (int mi = 0; mi < 4; ++mi)
      af[mi] = *(const bf16x8*)&As[buf][swzread(wr + mi * 16 + lr, q)];
#pragma unroll
    for (int ni = 0; ni < 4; ++ni)
      bfr[ni] = *(const bf16x8*)&Bs[buf][swzread(wc + ni * 16 + lr, q)];
#pragma unroll
    for (int mi = 0; mi < 4; ++mi)
#pragma unroll
      for (int ni = 0; ni < 4; ++ni)
        acc[mi][ni] = __builtin_amdgcn_mfma_f32_16x16x32_bf16(af[mi], bfr[ni], acc[mi][ni], 0, 0, 0);
    __syncthreads();
    buf ^= 1;
  }

#pragma unroll
  for (int mi = 0; mi < 4; ++mi) {
#pragma unroll
    for (int ni = 0; ni < 4; ++ni) {
      const int col = nt * 128 + wc + ni * 16 + lr;
#pragma unroll
      for (int r = 0; r < 4; ++r) {
        const int mrow = mt * 256 + wr + mi * 16 + q * 4 + r;
        if (mrow < n_e)
          po[(size_t)(rowbase + mrow) * HDIM + col] = bf1(acc[mi][ni][r]);
      }
    }
  }
}

// ---------------- combine: out[t] = sum_k w_k * po[row_k] -----------------
__global__ __launch_bounds__(256) void combine_kernel(
    const ushort* __restrict__ po, const int* __restrict__ inv,
    const float* __restrict__ tw, float* __restrict__ out)
{
  const int t = blockIdx.x;
  const int r0 = inv[t * 4 + 0], r1 = inv[t * 4 + 1];
  const int r2 = inv[t * 4 + 2], r3 = inv[t * 4 + 3];
  const float w0 = tw[t * 4 + 0], w1 = tw[t * 4 + 1];
  const float w2v = tw[t * 4 + 2], w3 = tw[t * 4 + 3];
  const int i = threadIdx.x;
  uint4 v0 = *(const uint4*)(po + (size_t)r0 * HDIM + i * 8);
  uint4 v1 = *(const uint4*)(po + (size_t)r1 * HDIM + i * 8);
  uint4 v2 = *(const uint4*)(po + (size_t)r2 * HDIM + i * 8);
  uint4 v3 = *(const uint4*)(po + (size_t)r3 * HDIM + i * 8);
  float o[8];
#pragma unroll
  for (int w = 0; w < 4; ++w) {
    const uint32_t a = (&v0.x)[w], b = (&v1.x)[w], c = (&v2.x)[w], d = (&v3.x)[w];
    o[w * 2 + 0] = w0 * __builtin_bit_cast(float, a << 16) +
                   w1 * __builtin_bit_cast(float, b << 16) +
                   w2v * __builtin_bit_cast(float, c << 16) +
                   w3 * __builtin_bit_cast(float, d << 16);
    o[w * 2 + 1] = w0 * __builtin_bit_cast(float, a & 0xffff0000u) +
                   w1 * __builtin_bit_cast(float, b & 0xffff0000u) +
                   w2v * __builtin_bit_cast(float, c & 0xffff0000u) +
                   w3 * __builtin_bit_cast(float, d & 0xffff0000u);
  }
  float4* o4 = (float4*)(out + (size_t)t * HDIM + i * 8);
  o4[0] = (float4){o[0], o[1], o[2], o[3]};
  o4[1] = (float4){o[4], o[5], o[6], o[7]};
}

extern "C" void kernel_launch(void* const* d_in, const int* in_sizes, int n_in,
                              void* d_out, int out_size, void* d_ws, size_t ws_size,
                              hipStream_t stream) {
  const float* x   = (const float*)d_in[0];
  const float* gw  = (const float*)d_in[1];
  const float* w1g = (const float*)d_in[2];
  const float* w1u = (const float*)d_in[3];
  const float* w2  = (const float*)d_in[4];
  float* out = (float*)d_out;

  char* ws = (char*)d_ws;
  // layout (bytes): xb 8MB @0; wbufG 64MB @8M; wbufU 64MB @72M;
  // wbuf2 64MB @136M; hbuf 16MB @200M; po 32MB @216M; idx @248M; ctrl.
  ushort* xb    = (ushort*)(ws + 0);
  ushort* wbufG = (ushort*)(ws + 8388608);
  ushort* wbufU = (ushort*)(ws + 75497472);
  ushort* wbuf2 = (ushort*)(ws + 142606336);
  ushort* hbuf  = (ushort*)(ws + 209715200);
  ushort* po    = (ushort*)(ws + 226492416);
  int*    tkid   = (int*)(ws + 260046848);
  float*  tkw    = (float*)(ws + 260046848 + 32768);
  int*    rowTok = (int*)(ws + 260046848 + 65536);
  int*    inv    = (int*)(ws + 260046848 + 98304);
  int*    ctrl   = (int*)(ws + 260177920);
  int* counts  = ctrl;           // 16
  int* offsets = ctrl + 32;      // 17
  int* nWA     = ctrl + 50;      // 1
  int* nWB     = ctrl + 51;      // 1
  int* wlA     = ctrl + 64;      // MAXB1 (752)
  int* wlB     = ctrl + 64 + MAXB1;  // MAXBB (752)

  // router + cvt(w1g) + cvt(w1u) overlap
  router_kernel<<<TTOK / 4 + 2 * NCVT, 256, 0, stream>>>(
      x, gw, xb, tkid, tkw, w1g, wbufG, w1u, wbufU);
  plan_scatter_kernel<<<1, 1024, 0, stream>>>(tkid, counts, offsets, nWA, nWB,
                                              wlA, wlB, rowTok, inv);
  // fused gate+up GEMM (BM=256, 8 waves) + silu epilogue; + cvt(w2) overlap
  gemm1_kernel<<<MAXB1 + NCVT1, 512, 0, stream>>>(
      xb, wbufG, wbufU, rowTok, counts, offsets, nWA, wlA, hbuf,
      w2, wbuf2);
  // down pass (BM=256, 8 waves)
  gemmB_kernel<<<MAXBB, 512, 0, stream>>>(hbuf, wbuf2, counts, offsets,
                                          nWB, wlB, po);
  combine_kernel<<<TTOK, 256, 0, stream>>>(po, inv, tkw, out);
}

// Round 24
// 309.422 us; speedup vs baseline: 1.1739x; 1.0024x over previous
//
#include <hip/hip_runtime.h>
#include <hip/hip_bf16.h>
#include <stdint.h>

#define NEXP 16
#define KSEL 4
#define HDIM 2048
#define IDIM 1024
#define TTOK 2048
#define NT1 16                   // gemm1 n-tiles (IDIM/64)
#define NTB 16                   // gemmB n-tiles (HDIM/128)
#define MAXT1 80                 // 128-row tiles max: 8192/128 + 16
#define MAXB1 (MAXT1 * NT1)      // 1280
#define MAXTB 47                 // 256-row tiles max
#define MAXBB (MAXTB * NTB)      // 752
#define NCVT 1024                // cvt blocks on router (256 thr)
#define NCVT1 512                // cvt blocks on gemm1 (512 thr)
#define NW8 ((NEXP * IDIM * HDIM) / 8)

typedef __attribute__((ext_vector_type(8))) short bf16x8;
typedef __attribute__((ext_vector_type(4))) float f32x4;
typedef unsigned int u32;

__device__ __forceinline__ uint32_t pack2(float a, float b) {
  __hip_bfloat162 h = __float22bfloat162_rn(float2{a, b});
  uint32_t u;
  __builtin_memcpy(&u, &h, 4);
  return u;
}
__device__ __forceinline__ ushort bf1(float a) {
  __hip_bfloat16 h = __float2bfloat16(a);
  ushort u;
  __builtin_memcpy(&u, &h, 2);
  return u;
}
__device__ __forceinline__ void gload16(const void* g, void* l) {
  __builtin_amdgcn_global_load_lds(
      (const __attribute__((address_space(1))) u32*)g,
      (__attribute__((address_space(3))) u32*)l, 16, 0, 0);
}
// bf16 tile [rows][32 bf16]: linear store, pre-XOR'd source chunk,
// XOR'd read chunk -> conflict-free (verified R3-R23).
__device__ __forceinline__ int swzread(int row, int q) {
  return row * 32 + ((q ^ ((row >> 1) & 3)) << 3);
}
__device__ __forceinline__ void cvt_bodyN(const float* __restrict__ src,
                                          ushort* __restrict__ dst,
                                          int idx0, int stride) {
  for (int i = idx0; i < NW8; i += stride) {
    f32x4 a = __builtin_nontemporal_load(((const f32x4*)src) + i * 2);
    f32x4 b = __builtin_nontemporal_load(((const f32x4*)src) + i * 2 + 1);
    uint4 t;
    t.x = pack2(a[0], a[1]); t.y = pack2(a[2], a[3]);
    t.z = pack2(b[0], b[1]); t.w = pack2(b[2], b[3]);
    ((uint4*)dst)[i] = t;
  }
}

// -- router (blocks 0..511) + piggyback cvt w1g / cvt w1u ------------------
__global__ __launch_bounds__(256) void router_kernel(
    const float* __restrict__ x, const float* __restrict__ gw,
    ushort* __restrict__ xb, int* __restrict__ topk_id,
    float* __restrict__ topk_w,
    const float* __restrict__ srcG, ushort* __restrict__ dstG,
    const float* __restrict__ srcU, ushort* __restrict__ dstU)
{
  if (blockIdx.x >= TTOK / 4 + NCVT) {
    cvt_bodyN(srcU, dstU,
              (blockIdx.x - (TTOK / 4 + NCVT)) * 256 + threadIdx.x, NCVT * 256);
    return;
  }
  if (blockIdx.x >= TTOK / 4) {
    cvt_bodyN(srcG, dstG,
              (blockIdx.x - TTOK / 4) * 256 + threadIdx.x, NCVT * 256);
    return;
  }
  const int wid = threadIdx.x >> 6;
  const int lane = threadIdx.x & 63;
  const int t = blockIdx.x * 4 + wid;
  const float4* x4 = (const float4*)(x + (size_t)t * HDIM);
  const float4* gw4 = (const float4*)gw;
  float acc[NEXP];
#pragma unroll
  for (int e = 0; e < NEXP; ++e) acc[e] = 0.f;
#pragma unroll
  for (int i = 0; i < HDIM / 256; ++i) {
    const int idx = i * 64 + lane;
    float4 xv = x4[idx];
    uint2 xp;
    xp.x = pack2(xv.x, xv.y);
    xp.y = pack2(xv.z, xv.w);
    *(uint2*)(xb + (size_t)t * HDIM + idx * 4) = xp;
#pragma unroll
    for (int e = 0; e < NEXP; ++e) {
      float4 wv = gw4[e * (HDIM / 4) + idx];
      acc[e] += xv.x * wv.x + xv.y * wv.y + xv.z * wv.z + xv.w * wv.w;
    }
  }
#pragma unroll
  for (int e = 0; e < NEXP; ++e) {
#pragma unroll
    for (int off = 32; off >= 1; off >>= 1)
      acc[e] += __shfl_xor(acc[e], off);
  }
  if (lane == 0) {
    unsigned taken = 0;
    float vals[KSEL];
    int ids[KSEL];
#pragma unroll
    for (int k = 0; k < KSEL; ++k) {
      float bv = -3.4e38f; int bi = 0;
      for (int e = 0; e < NEXP; ++e)
        if (!((taken >> e) & 1u) && acc[e] > bv) { bv = acc[e]; bi = e; }
      taken |= 1u << bi; vals[k] = bv; ids[k] = bi;
    }
    float m = vals[0], s = 0.f, w[KSEL];
#pragma unroll
    for (int k = 0; k < KSEL; ++k) { w[k] = __expf(vals[k] - m); s += w[k]; }
    float is = 1.f / s;
#pragma unroll
    for (int k = 0; k < KSEL; ++k) {
      topk_id[t * KSEL + k] = ids[k];
      topk_w[t * KSEL + k] = w[k] * is;
    }
  }
}

// --- plan+scatter: dual granularity (gemm1 128-row, gemmB 256-row) --------
__global__ __launch_bounds__(1024) void plan_scatter_kernel(
    const int* __restrict__ topk_id, int* __restrict__ counts,
    int* __restrict__ offsets, int* __restrict__ nWA, int* __restrict__ nWB,
    int* __restrict__ wlA, int* __restrict__ wlB,
    int* __restrict__ rowTok, int* __restrict__ inv)
{
  __shared__ int cnt[NEXP], off[NEXP], cur[NEXP];
  __shared__ int t1[NEXP], p1[NEXP], tB[NEXP], pB[NEXP];
  const int tid = threadIdx.x;
  if (tid < NEXP) { cnt[tid] = 0; cur[tid] = 0; }
  __syncthreads();
  for (int i = tid; i < TTOK * KSEL; i += 1024)
    atomicAdd(&cnt[topk_id[i]], 1);
  __syncthreads();
  if (tid == 0) {
    int s = 0, a = 0, b = 0;
    for (int e = 0; e < NEXP; ++e) {
      off[e] = s; s += cnt[e];
      t1[e] = (cnt[e] + 127) >> 7;  p1[e] = a;  a += t1[e];
      tB[e] = (cnt[e] + 255) >> 8;  pB[e] = b;  b += tB[e];
    }
    *nWA = a * NT1;
    *nWB = b * NTB;
  }
  __syncthreads();
  if (tid < NEXP) {
    counts[tid] = cnt[tid];
    offsets[tid] = off[tid];
    const int e = tid, T = t1[e];
    int idx = p1[e] * NT1;
    for (int nt = 0; nt < NT1; ++nt)
      for (int mt = 0; mt < T; ++mt)
        wlA[idx++] = (e << 12) | (nt << 6) | mt;
  } else if (tid < 2 * NEXP) {
    const int e = tid - NEXP, T = tB[e];
    int idx = pB[e] * NTB;
    for (int nt = 0; nt < NTB; ++nt)
      for (int mt = 0; mt < T; ++mt)
        wlB[idx++] = (e << 12) | (nt << 6) | mt;
  }
  for (int i = tid; i < TTOK * KSEL; i += 1024) {
    const int e = topk_id[i];
    const int pos = atomicAdd(&cur[e], 1);
    const int row = off[e] + pos;
    rowTok[row] = i >> 2;
    inv[i] = row;
  }
}

// -- gemm1: BM=128, 8 waves, 3-buffer LDS pipeline with counted vmcnt(2).
//    Waves 0-3 compute G (64r x 32c each), waves 4-7 compute U; epilogue
//    exchanges U accs via LDS, G-waves write h = silu(g)*u.
//    LDS 48 KB total (same as R23). Blocks >= MAXB1: cvt(w2). -------------
__global__ __launch_bounds__(512) void gemm1_kernel(
    const ushort* __restrict__ xb,
    const ushort* __restrict__ wG, const ushort* __restrict__ wU,
    const int* __restrict__ rowTok, const int* __restrict__ counts,
    const int* __restrict__ offsets, const int* __restrict__ nW,
    const int* __restrict__ wl, ushort* __restrict__ hbuf,
    const float* __restrict__ cvsrc, ushort* __restrict__ cvdst)
{
  if (blockIdx.x >= MAXB1) {
    cvt_bodyN(cvsrc, cvdst,
              (blockIdx.x - MAXB1) * 512 + threadIdx.x, NCVT1 * 512);
    return;
  }
  const int nTot = *nW;
  const int L = (blockIdx.x & 7) * (MAXB1 / 8) + (blockIdx.x >> 3);
  if (L >= nTot) return;
  const int w = wl[L];
  const int e = w >> 12, nt = (w >> 6) & 63, mt = w & 63;
  const int n_e = counts[e], rowbase = offsets[e];

  // 49152 B: As 3x8KB @0; Bg 3x4KB @24576B; Bu 3x4KB @36864B
  __shared__ ushort lds[24576];
#define AS(b) (lds + (b) * 4096)
#define BG(b) (lds + 12288 + (b) * 2048)
#define BU(b) (lds + 18432 + (b) * 2048)

  const int tid = threadIdx.x;
  const int lane = tid & 63;
  const int wv = tid >> 6;             // 0..7

  // A staging: row = tid>>2 (0..127), chunk = tid&3
  const int arow = tid >> 2;
  const int ckA = tid & 3;
  const int schA = (ckA ^ ((arow >> 1) & 3)) << 3;
  const int agr = mt * 128 + arow;
  const int tokA = rowTok[rowbase + (agr < n_e ? agr : n_e - 1)];
  const ushort* pA = xb + (size_t)tokA * HDIM + schA;
  // B staging: tid<256 -> Bg row (tid>>2); tid>=256 -> Bu row ((tid-256)>>2)
  const int bloc = tid & 255;
  const int brow = bloc >> 2;
  const int ckB = bloc & 3;
  const int schB = (ckB ^ ((brow >> 1) & 3)) << 3;
  const size_t wbase = (size_t)e * IDIM * HDIM;
  const ushort* pB = ((tid < 256) ? wG : wU) + wbase +
                     (size_t)(nt * 64 + brow) * HDIM + schB;

  // compute geometry: wave wv: Mgrp = wv>>2 (rows), ng = wv&3
  const int wr = (wv >> 2) << 6;       // 0/64
  const int ng = wv & 3;               // 0,1 -> G cols 0/32 ; 2,3 -> U cols 0/32
  const bool isU = ng >= 2;
  const int wc = (ng & 1) << 5;        // 0/32
  const int lr = lane & 15;
  const int q = lane >> 4;

  f32x4 acc[4][2];
#pragma unroll
  for (int i = 0; i < 4; ++i)
#pragma unroll
    for (int j = 0; j < 2; ++j) acc[i][j] = (f32x4){0.f, 0.f, 0.f, 0.f};

  auto STAGE = [&](int b) {
    gload16(pA, AS(b) + tid * 8);
    if (tid < 256) gload16(pB, BG(b) + bloc * 8);
    else           gload16(pB, BU(b) + bloc * 8);
    pA += 32; pB += 32;
  };

  const int NTK = HDIM / 32;  // 64
  STAGE(0);
  STAGE(1);
  asm volatile("s_waitcnt vmcnt(2)" ::: "memory");   // stage0 landed
  __builtin_amdgcn_s_barrier();
  __builtin_amdgcn_sched_barrier(0);
  int buf = 0;
  for (int kt = 0; kt < NTK; ++kt) {
    if (kt + 2 < NTK) STAGE(buf == 0 ? 2 : buf - 1);  // (kt+2)%3
    const ushort* bsrc = isU ? BU(buf) : BG(buf);
    bf16x8 af[4], bf[2];
#pragma unroll
    for (int mi = 0; mi < 4; ++mi)
      af[mi] = *(const bf16x8*)&AS(buf)[swzread(wr + mi * 16 + lr, q)];
#pragma unroll
    for (int ni = 0; ni < 2; ++ni)
      bf[ni] = *(const bf16x8*)&bsrc[swzread(wc + ni * 16 + lr, q)];
#pragma unroll
    for (int mi = 0; mi < 4; ++mi)
#pragma unroll
      for (int ni = 0; ni < 2; ++ni)
        acc[mi][ni] = __builtin_amdgcn_mfma_f32_16x16x32_bf16(af[mi], bf[ni], acc[mi][ni], 0, 0, 0);
    if (kt + 1 < NTK) {
      if (kt + 2 < NTK)
        asm volatile("s_waitcnt vmcnt(2)" ::: "memory");  // kt+1 landed; kt+2 in flight
      else
        asm volatile("s_waitcnt vmcnt(0)" ::: "memory");  // tail drain
      __builtin_amdgcn_s_barrier();
      __builtin_amdgcn_sched_barrier(0);
    }
    buf = (buf == 2) ? 0 : buf + 1;
  }

  // ---- epilogue: exchange U accs via LDS (reuse as f32 scratch 32KB) ----
  __syncthreads();                      // all LDS reads done
  float* uex = (float*)lds;             // [128][64] fp32
  if (isU) {
    const int ucol0 = ((ng - 2) << 5);
#pragma unroll
    for (int mi = 0; mi < 4; ++mi)
#pragma unroll
      for (int ni = 0; ni < 2; ++ni)
#pragma unroll
        for (int r = 0; r < 4; ++r)
          uex[(wr + mi * 16 + q * 4 + r) * 64 + ucol0 + ni * 16 + lr] = acc[mi][ni][r];
  }
  __syncthreads();
  if (!isU) {
    const int gcol0 = (ng << 5);
#pragma unroll
    for (int mi = 0; mi < 4; ++mi)
#pragma unroll
      for (int ni = 0; ni < 2; ++ni) {
        const int lcol = gcol0 + ni * 16 + lr;
        const int col = nt * 64 + lcol;
#pragma unroll
        for (int r = 0; r < 4; ++r) {
          const int lrow = wr + mi * 16 + q * 4 + r;
          const int mrow = mt * 128 + lrow;
          if (mrow < n_e) {
            const float gv = acc[mi][ni][r];
            const float uv = uex[lrow * 64 + lcol];
            const float hv = (gv / (1.f + __expf(-gv))) * uv;
            hbuf[(size_t)(rowbase + mrow) * IDIM + col] = bf1(hv);
          }
        }
      }
  }
#undef AS
#undef BG
#undef BU
}

// -- gemmB BM=256, 8 waves (R23 winner, unchanged) -------------------------
__global__ __launch_bounds__(512) void gemmB_kernel(
    const ushort* __restrict__ hb, const ushort* __restrict__ wb,
    const int* __restrict__ counts, const int* __restrict__ offsets,
    const int* __restrict__ nW, const int* __restrict__ wl,
    ushort* __restrict__ po)
{
  const int nTot = *nW;
  const int L = (blockIdx.x & 7) * (MAXBB / 8) + (blockIdx.x >> 3);
  if (L >= nTot) return;
  const int w = wl[L];
  const int e = w >> 12, nt = (w >> 6) & 63, mt = w & 63;
  const int n_e = counts[e], rowbase = offsets[e];

  __shared__ ushort As[2][256 * 32];
  __shared__ ushort Bs[2][128 * 32];

  const int tid = threadIdx.x;
  const int lane = tid & 63;
  const int wid = tid >> 6;

  const int lr4 = lane >> 2;
  const int ckA = lane & 3;
  const int arl0 = wid * 32 + lr4;
  const int arl1 = wid * 32 + 16 + lr4;
  const int schA0 = (ckA ^ ((arl0 >> 1) & 3)) << 3;
  const int schA1 = (ckA ^ ((arl1 >> 1) & 3)) << 3;
  const int ag0 = mt * 256 + arl0, ag1 = mt * 256 + arl1;
  const int g0 = rowbase + (ag0 < n_e ? ag0 : n_e - 1);
  const int g1 = rowbase + (ag1 < n_e ? ag1 : n_e - 1);
  const ushort* pA0 = hb + (size_t)g0 * IDIM + schA0;
  const ushort* pA1 = hb + (size_t)g1 * IDIM + schA1;
  const int brl = wid * 16 + lr4;
  const int schB = (ckA ^ ((brl >> 1) & 3)) << 3;
  const size_t wbase = (size_t)e * HDIM * IDIM;
  const ushort* pB = wb + wbase + (size_t)(nt * 128 + brl) * IDIM + schB;

  const int wr = (wid >> 1) << 6;
  const int wc = (wid & 1) << 6;
  const int lr = lane & 15;
  const int q = lane >> 4;

  f32x4 acc[4][4];
#pragma unroll
  for (int i = 0; i < 4; ++i)
#pragma unroll
    for (int j = 0; j < 4; ++j) acc[i][j] = (f32x4){0.f, 0.f, 0.f, 0.f};

  auto STAGE = [&](int b) {
    gload16(pA0, &As[b][wid * 1024 + lane * 8]);
    gload16(pA1, &As[b][wid * 1024 + 512 + lane * 8]);
    gload16(pB, &Bs[b][wid * 512 + lane * 8]);
    pA0 += 32; pA1 += 32; pB += 32;
  };

  const int NTK = IDIM / 32;  // 32
  STAGE(0);
  __syncthreads();
  int buf = 0;
  for (int kt = 0; kt < NTK; ++kt) {
    if (kt + 1 < NTK) STAGE(buf ^ 1);
    bf16x8 af[4], bfr[4];
#pragma unroll
    for (int mi = 0; mi < 4; ++mi)
      af[mi] = *(const bf16x8*)&As[buf][swzread(wr + mi * 16 + lr, q)];
#pragma unroll
    for (int ni = 0; ni < 4; ++ni)
      bfr[ni] = *(const bf16x8*)&Bs[buf][swzread(wc + ni * 16 + lr, q)];
#pragma unroll
    for (int mi = 0; mi < 4; ++mi)
#pragma unroll
      for (int ni = 0; ni < 4; ++ni)
        acc[mi][ni] = __builtin_amdgcn_mfma_f32_16x16x32_bf16(af[mi], bfr[ni], acc[mi][ni], 0, 0, 0);
    __syncthreads();
    buf ^= 1;
  }

#pragma unroll
  for (int mi = 0; mi < 4; ++mi) {
#pragma unroll
    for (int ni = 0; ni < 4; ++ni) {
      const int col = nt * 128 + wc + ni * 16 + lr;
#pragma unroll
      for (int r = 0; r < 4; ++r) {
        const int mrow = mt * 256 + wr + mi * 16 + q * 4 + r;
        if (mrow < n_e)
          po[(size_t)(rowbase + mrow) * HDIM + col] = bf1(acc[mi][ni][r]);
      }
    }
  }
}

// ---------------- combine: out[t] = sum_k w_k * po[row_k] -----------------
__global__ __launch_bounds__(256) void combine_kernel(
    const ushort* __restrict__ po, const int* __restrict__ inv,
    const float* __restrict__ tw, float* __restrict__ out)
{
  const int t = blockIdx.x;
  const int r0 = inv[t * 4 + 0], r1 = inv[t * 4 + 1];
  const int r2 = inv[t * 4 + 2], r3 = inv[t * 4 + 3];
  const float w0 = tw[t * 4 + 0], w1 = tw[t * 4 + 1];
  const float w2v = tw[t * 4 + 2], w3 = tw[t * 4 + 3];
  const int i = threadIdx.x;
  uint4 v0 = *(const uint4*)(po + (size_t)r0 * HDIM + i * 8);
  uint4 v1 = *(const uint4*)(po + (size_t)r1 * HDIM + i * 8);
  uint4 v2 = *(const uint4*)(po + (size_t)r2 * HDIM + i * 8);
  uint4 v3 = *(const uint4*)(po + (size_t)r3 * HDIM + i * 8);
  float o[8];
#pragma unroll
  for (int w = 0; w < 4; ++w) {
    const uint32_t a = (&v0.x)[w], b = (&v1.x)[w], c = (&v2.x)[w], d = (&v3.x)[w];
    o[w * 2 + 0] = w0 * __builtin_bit_cast(float, a << 16) +
                   w1 * __builtin_bit_cast(float, b << 16) +
                   w2v * __builtin_bit_cast(float, c << 16) +
                   w3 * __builtin_bit_cast(float, d << 16);
    o[w * 2 + 1] = w0 * __builtin_bit_cast(float, a & 0xffff0000u) +
                   w1 * __builtin_bit_cast(float, b & 0xffff0000u) +
                   w2v * __builtin_bit_cast(float, c & 0xffff0000u) +
                   w3 * __builtin_bit_cast(float, d & 0xffff0000u);
  }
  float4* o4 = (float4*)(out + (size_t)t * HDIM + i * 8);
  o4[0] = (float4){o[0], o[1], o[2], o[3]};
  o4[1] = (float4){o[4], o[5], o[6], o[7]};
}

extern "C" void kernel_launch(void* const* d_in, const int* in_sizes, int n_in,
                              void* d_out, int out_size, void* d_ws, size_t ws_size,
                              hipStream_t stream) {
  const float* x   = (const float*)d_in[0];
  const float* gw  = (const float*)d_in[1];
  const float* w1g = (const float*)d_in[2];
  const float* w1u = (const float*)d_in[3];
  const float* w2  = (const float*)d_in[4];
  float* out = (float*)d_out;

  char* ws = (char*)d_ws;
  ushort* xb    = (ushort*)(ws + 0);
  ushort* wbufG = (ushort*)(ws + 8388608);
  ushort* wbufU = (ushort*)(ws + 75497472);
  ushort* wbuf2 = (ushort*)(ws + 142606336);
  ushort* hbuf  = (ushort*)(ws + 209715200);
  ushort* po    = (ushort*)(ws + 226492416);
  int*    tkid   = (int*)(ws + 260046848);
  float*  tkw    = (float*)(ws + 260046848 + 32768);
  int*    rowTok = (int*)(ws + 260046848 + 65536);
  int*    inv    = (int*)(ws + 260046848 + 98304);
  int*    ctrl   = (int*)(ws + 260177920);
  int* counts  = ctrl;           // 16
  int* offsets = ctrl + 32;      // 17
  int* nWA     = ctrl + 50;      // 1
  int* nWB     = ctrl + 51;      // 1
  int* wlA     = ctrl + 64;      // MAXB1 (1280)
  int* wlB     = ctrl + 64 + MAXB1;  // MAXBB (752)

  router_kernel<<<TTOK / 4 + 2 * NCVT, 256, 0, stream>>>(
      x, gw, xb, tkid, tkw, w1g, wbufG, w1u, wbufU);
  plan_scatter_kernel<<<1, 1024, 0, stream>>>(tkid, counts, offsets, nWA, nWB,
                                              wlA, wlB, rowTok, inv);
  gemm1_kernel<<<MAXB1 + NCVT1, 512, 0, stream>>>(
      xb, wbufG, wbufU, rowTok, counts, offsets, nWA, wlA, hbuf,
      w2, wbuf2);
  gemmB_kernel<<<MAXBB, 512, 0, stream>>>(hbuf, wbuf2, counts, offsets,
                                          nWB, wlB, po);
  combine_kernel<<<TTOK, 256, 0, stream>>>(po, inv, tkw, out);
}

// Round 25
// 305.951 us; speedup vs baseline: 1.1872x; 1.0113x over previous
//
#include <hip/hip_runtime.h>
#include <hip/hip_bf16.h>
#include <stdint.h>

#define NEXP 16
#define KSEL 4
#define HDIM 2048
#define IDIM 1024
#define TTOK 2048
#define NT1 16                   // gemm1 n-tiles (IDIM/64)
#define NTB 16                   // gemmB n-tiles (HDIM/128)
#define MAXT1 80                 // 128-row tiles max
#define MAXB1 (MAXT1 * NT1)      // 1280
#define MAXTB 47                 // 256-row tiles max
#define MAXBB (MAXTB * NTB)      // 752
#define NCVT 1024                // cvt blocks on router (256 thr)
#define NCVT1 512                // cvt blocks on gemm1 (512 thr)
#define NW8 ((NEXP * IDIM * HDIM) / 8)

typedef __attribute__((ext_vector_type(8))) short bf16x8;
typedef __attribute__((ext_vector_type(4))) float f32x4;
typedef unsigned int u32;

__device__ __forceinline__ uint32_t pack2(float a, float b) {
  __hip_bfloat162 h = __float22bfloat162_rn(float2{a, b});
  uint32_t u;
  __builtin_memcpy(&u, &h, 4);
  return u;
}
__device__ __forceinline__ ushort bf1(float a) {
  __hip_bfloat16 h = __float2bfloat16(a);
  ushort u;
  __builtin_memcpy(&u, &h, 2);
  return u;
}
__device__ __forceinline__ void gload16(const void* g, void* l) {
  __builtin_amdgcn_global_load_lds(
      (const __attribute__((address_space(1))) u32*)g,
      (__attribute__((address_space(3))) u32*)l, 16, 0, 0);
}
// bf16 tile [rows][32 bf16]: linear store, pre-XOR'd source chunk,
// XOR'd read chunk -> conflict-free (verified R3-R24).
__device__ __forceinline__ int swzread(int row, int q) {
  return row * 32 + ((q ^ ((row >> 1) & 3)) << 3);
}
__device__ __forceinline__ void cvt_bodyN(const float* __restrict__ src,
                                          ushort* __restrict__ dst,
                                          int idx0, int stride) {
  for (int i = idx0; i < NW8; i += stride) {
    f32x4 a = __builtin_nontemporal_load(((const f32x4*)src) + i * 2);
    f32x4 b = __builtin_nontemporal_load(((const f32x4*)src) + i * 2 + 1);
    uint4 t;
    t.x = pack2(a[0], a[1]); t.y = pack2(a[2], a[3]);
    t.z = pack2(b[0], b[1]); t.w = pack2(b[2], b[3]);
    ((uint4*)dst)[i] = t;
  }
}

// -- router (blocks 0..511) + piggyback cvt w1g / cvt w1u ------------------
__global__ __launch_bounds__(256) void router_kernel(
    const float* __restrict__ x, const float* __restrict__ gw,
    ushort* __restrict__ xb, int* __restrict__ topk_id,
    float* __restrict__ topk_w,
    const float* __restrict__ srcG, ushort* __restrict__ dstG,
    const float* __restrict__ srcU, ushort* __restrict__ dstU)
{
  if (blockIdx.x >= TTOK / 4 + NCVT) {
    cvt_bodyN(srcU, dstU,
              (blockIdx.x - (TTOK / 4 + NCVT)) * 256 + threadIdx.x, NCVT * 256);
    return;
  }
  if (blockIdx.x >= TTOK / 4) {
    cvt_bodyN(srcG, dstG,
              (blockIdx.x - TTOK / 4) * 256 + threadIdx.x, NCVT * 256);
    return;
  }
  const int wid = threadIdx.x >> 6;
  const int lane = threadIdx.x & 63;
  const int t = blockIdx.x * 4 + wid;
  const float4* x4 = (const float4*)(x + (size_t)t * HDIM);
  const float4* gw4 = (const float4*)gw;
  float acc[NEXP];
#pragma unroll
  for (int e = 0; e < NEXP; ++e) acc[e] = 0.f;
#pragma unroll
  for (int i = 0; i < HDIM / 256; ++i) {
    const int idx = i * 64 + lane;
    float4 xv = x4[idx];
    uint2 xp;
    xp.x = pack2(xv.x, xv.y);
    xp.y = pack2(xv.z, xv.w);
    *(uint2*)(xb + (size_t)t * HDIM + idx * 4) = xp;
#pragma unroll
    for (int e = 0; e < NEXP; ++e) {
      float4 wv = gw4[e * (HDIM / 4) + idx];
      acc[e] += xv.x * wv.x + xv.y * wv.y + xv.z * wv.z + xv.w * wv.w;
    }
  }
#pragma unroll
  for (int e = 0; e < NEXP; ++e) {
#pragma unroll
    for (int off = 32; off >= 1; off >>= 1)
      acc[e] += __shfl_xor(acc[e], off);
  }
  if (lane == 0) {
    unsigned taken = 0;
    float vals[KSEL];
    int ids[KSEL];
#pragma unroll
    for (int k = 0; k < KSEL; ++k) {
      float bv = -3.4e38f; int bi = 0;
      for (int e = 0; e < NEXP; ++e)
        if (!((taken >> e) & 1u) && acc[e] > bv) { bv = acc[e]; bi = e; }
      taken |= 1u << bi; vals[k] = bv; ids[k] = bi;
    }
    float m = vals[0], s = 0.f, w[KSEL];
#pragma unroll
    for (int k = 0; k < KSEL; ++k) { w[k] = __expf(vals[k] - m); s += w[k]; }
    float is = 1.f / s;
#pragma unroll
    for (int k = 0; k < KSEL; ++k) {
      topk_id[t * KSEL + k] = ids[k];
      topk_w[t * KSEL + k] = w[k] * is;
    }
  }
}

// --- plan+scatter: dual granularity (gemm1 128-row, gemmB 256-row) --------
__global__ __launch_bounds__(1024) void plan_scatter_kernel(
    const int* __restrict__ topk_id, int* __restrict__ counts,
    int* __restrict__ offsets, int* __restrict__ nWA, int* __restrict__ nWB,
    int* __restrict__ wlA, int* __restrict__ wlB,
    int* __restrict__ rowTok, int* __restrict__ inv)
{
  __shared__ int cnt[NEXP], off[NEXP], cur[NEXP];
  __shared__ int t1[NEXP], p1[NEXP], tB[NEXP], pB[NEXP];
  const int tid = threadIdx.x;
  if (tid < NEXP) { cnt[tid] = 0; cur[tid] = 0; }
  __syncthreads();
  for (int i = tid; i < TTOK * KSEL; i += 1024)
    atomicAdd(&cnt[topk_id[i]], 1);
  __syncthreads();
  if (tid == 0) {
    int s = 0, a = 0, b = 0;
    for (int e = 0; e < NEXP; ++e) {
      off[e] = s; s += cnt[e];
      t1[e] = (cnt[e] + 127) >> 7;  p1[e] = a;  a += t1[e];
      tB[e] = (cnt[e] + 255) >> 8;  pB[e] = b;  b += tB[e];
    }
    *nWA = a * NT1;
    *nWB = b * NTB;
  }
  __syncthreads();
  if (tid < NEXP) {
    counts[tid] = cnt[tid];
    offsets[tid] = off[tid];
    const int e = tid, T = t1[e];
    int idx = p1[e] * NT1;
    for (int nt = 0; nt < NT1; ++nt)
      for (int mt = 0; mt < T; ++mt)
        wlA[idx++] = (e << 12) | (nt << 6) | mt;
  } else if (tid < 2 * NEXP) {
    const int e = tid - NEXP, T = tB[e];
    int idx = pB[e] * NTB;
    for (int nt = 0; nt < NTB; ++nt)
      for (int mt = 0; mt < T; ++mt)
        wlB[idx++] = (e << 12) | (nt << 6) | mt;
  }
  for (int i = tid; i < TTOK * KSEL; i += 1024) {
    const int e = topk_id[i];
    const int pos = atomicAdd(&cur[e], 1);
    const int row = off[e] + pos;
    rowTok[row] = i >> 2;
    inv[i] = row;
  }
}

// -- gemm1: BM=128, 8 waves, 3-buffer counted-vmcnt pipeline (R24 body).
//    CHANGE (R25): cvt(w2) blocks come FIRST in the grid so the BW-bound
//    cvt co-resides with the latency-bound GEMM from t=0 (no tail-serialize).
__global__ __launch_bounds__(512) void gemm1_kernel(
    const ushort* __restrict__ xb,
    const ushort* __restrict__ wG, const ushort* __restrict__ wU,
    const int* __restrict__ rowTok, const int* __restrict__ counts,
    const int* __restrict__ offsets, const int* __restrict__ nW,
    const int* __restrict__ wl, ushort* __restrict__ hbuf,
    const float* __restrict__ cvsrc, ushort* __restrict__ cvdst)
{
  if (blockIdx.x < NCVT1) {
    cvt_bodyN(cvsrc, cvdst, blockIdx.x * 512 + threadIdx.x, NCVT1 * 512);
    return;
  }
  const int bid = blockIdx.x - NCVT1;
  const int nTot = *nW;
  const int L = (bid & 7) * (MAXB1 / 8) + (bid >> 3);
  if (L >= nTot) return;
  const int w = wl[L];
  const int e = w >> 12, nt = (w >> 6) & 63, mt = w & 63;
  const int n_e = counts[e], rowbase = offsets[e];

  // 49152 B: As 3x8KB @0; Bg 3x4KB @24576B; Bu 3x4KB @36864B
  __shared__ ushort lds[24576];
#define AS(b) (lds + (b) * 4096)
#define BG(b) (lds + 12288 + (b) * 2048)
#define BU(b) (lds + 18432 + (b) * 2048)

  const int tid = threadIdx.x;
  const int lane = tid & 63;
  const int wv = tid >> 6;             // 0..7

  const int arow = tid >> 2;
  const int ckA = tid & 3;
  const int schA = (ckA ^ ((arow >> 1) & 3)) << 3;
  const int agr = mt * 128 + arow;
  const int tokA = rowTok[rowbase + (agr < n_e ? agr : n_e - 1)];
  const ushort* pA = xb + (size_t)tokA * HDIM + schA;
  const int bloc = tid & 255;
  const int brow = bloc >> 2;
  const int ckB = bloc & 3;
  const int schB = (ckB ^ ((brow >> 1) & 3)) << 3;
  const size_t wbase = (size_t)e * IDIM * HDIM;
  const ushort* pB = ((tid < 256) ? wG : wU) + wbase +
                     (size_t)(nt * 64 + brow) * HDIM + schB;

  const int wr = (wv >> 2) << 6;       // 0/64
  const int ng = wv & 3;
  const bool isU = ng >= 2;
  const int wc = (ng & 1) << 5;        // 0/32
  const int lr = lane & 15;
  const int q = lane >> 4;

  f32x4 acc[4][2];
#pragma unroll
  for (int i = 0; i < 4; ++i)
#pragma unroll
    for (int j = 0; j < 2; ++j) acc[i][j] = (f32x4){0.f, 0.f, 0.f, 0.f};

  auto STAGE = [&](int b) {
    gload16(pA, AS(b) + tid * 8);
    if (tid < 256) gload16(pB, BG(b) + bloc * 8);
    else           gload16(pB, BU(b) + bloc * 8);
    pA += 32; pB += 32;
  };

  const int NTK = HDIM / 32;  // 64
  STAGE(0);
  STAGE(1);
  asm volatile("s_waitcnt vmcnt(2)" ::: "memory");
  __builtin_amdgcn_s_barrier();
  __builtin_amdgcn_sched_barrier(0);
  int buf = 0;
  for (int kt = 0; kt < NTK; ++kt) {
    if (kt + 2 < NTK) STAGE(buf == 0 ? 2 : buf - 1);
    const ushort* bsrc = isU ? BU(buf) : BG(buf);
    bf16x8 af[4], bf[2];
#pragma unroll
    for (int mi = 0; mi < 4; ++mi)
      af[mi] = *(const bf16x8*)&AS(buf)[swzread(wr + mi * 16 + lr, q)];
#pragma unroll
    for (int ni = 0; ni < 2; ++ni)
      bf[ni] = *(const bf16x8*)&bsrc[swzread(wc + ni * 16 + lr, q)];
#pragma unroll
    for (int mi = 0; mi < 4; ++mi)
#pragma unroll
      for (int ni = 0; ni < 2; ++ni)
        acc[mi][ni] = __builtin_amdgcn_mfma_f32_16x16x32_bf16(af[mi], bf[ni], acc[mi][ni], 0, 0, 0);
    if (kt + 1 < NTK) {
      if (kt + 2 < NTK)
        asm volatile("s_waitcnt vmcnt(2)" ::: "memory");
      else
        asm volatile("s_waitcnt vmcnt(0)" ::: "memory");
      __builtin_amdgcn_s_barrier();
      __builtin_amdgcn_sched_barrier(0);
    }
    buf = (buf == 2) ? 0 : buf + 1;
  }

  // ---- epilogue: exchange U accs via LDS (reuse as f32 scratch 32KB) ----
  __syncthreads();
  float* uex = (float*)lds;             // [128][64] fp32
  if (isU) {
    const int ucol0 = ((ng - 2) << 5);
#pragma unroll
    for (int mi = 0; mi < 4; ++mi)
#pragma unroll
      for (int ni = 0; ni < 2; ++ni)
#pragma unroll
        for (int r = 0; r < 4; ++r)
          uex[(wr + mi * 16 + q * 4 + r) * 64 + ucol0 + ni * 16 + lr] = acc[mi][ni][r];
  }
  __syncthreads();
  if (!isU) {
    const int gcol0 = (ng << 5);
#pragma unroll
    for (int mi = 0; mi < 4; ++mi)
#pragma unroll
      for (int ni = 0; ni < 2; ++ni) {
        const int lcol = gcol0 + ni * 16 + lr;
        const int col = nt * 64 + lcol;
#pragma unroll
        for (int r = 0; r < 4; ++r) {
          const int lrow = wr + mi * 16 + q * 4 + r;
          const int mrow = mt * 128 + lrow;
          if (mrow < n_e) {
            const float gv = acc[mi][ni][r];
            const float uv = uex[lrow * 64 + lcol];
            const float hv = (gv / (1.f + __expf(-gv))) * uv;
            hbuf[(size_t)(rowbase + mrow) * IDIM + col] = bf1(hv);
          }
        }
      }
  }
#undef AS
#undef BG
#undef BU
}

// -- gemmB BM=256, 8 waves (R23 winner, unchanged) -------------------------
__global__ __launch_bounds__(512) void gemmB_kernel(
    const ushort* __restrict__ hb, const ushort* __restrict__ wb,
    const int* __restrict__ counts, const int* __restrict__ offsets,
    const int* __restrict__ nW, const int* __restrict__ wl,
    ushort* __restrict__ po)
{
  const int nTot = *nW;
  const int L = (blockIdx.x & 7) * (MAXBB / 8) + (blockIdx.x >> 3);
  if (L >= nTot) return;
  const int w = wl[L];
  const int e = w >> 12, nt = (w >> 6) & 63, mt = w & 63;
  const int n_e = counts[e], rowbase = offsets[e];

  __shared__ ushort As[2][256 * 32];
  __shared__ ushort Bs[2][128 * 32];

  const int tid = threadIdx.x;
  const int lane = tid & 63;
  const int wid = tid >> 6;

  const int lr4 = lane >> 2;
  const int ckA = lane & 3;
  const int arl0 = wid * 32 + lr4;
  const int arl1 = wid * 32 + 16 + lr4;
  const int schA0 = (ckA ^ ((arl0 >> 1) & 3)) << 3;
  const int schA1 = (ckA ^ ((arl1 >> 1) & 3)) << 3;
  const int ag0 = mt * 256 + arl0, ag1 = mt * 256 + arl1;
  const int g0 = rowbase + (ag0 < n_e ? ag0 : n_e - 1);
  const int g1 = rowbase + (ag1 < n_e ? ag1 : n_e - 1);
  const ushort* pA0 = hb + (size_t)g0 * IDIM + schA0;
  const ushort* pA1 = hb + (size_t)g1 * IDIM + schA1;
  const int brl = wid * 16 + lr4;
  const int schB = (ckA ^ ((brl >> 1) & 3)) << 3;
  const size_t wbase = (size_t)e * HDIM * IDIM;
  const ushort* pB = wb + wbase + (size_t)(nt * 128 + brl) * IDIM + schB;

  const int wr = (wid >> 1) << 6;
  const int wc = (wid & 1) << 6;
  const int lr = lane & 15;
  const int q = lane >> 4;

  f32x4 acc[4][4];
#pragma unroll
  for (int i = 0; i < 4; ++i)
#pragma unroll
    for (int j = 0; j < 4; ++j) acc[i][j] = (f32x4){0.f, 0.f, 0.f, 0.f};

  auto STAGE = [&](int b) {
    gload16(pA0, &As[b][wid * 1024 + lane * 8]);
    gload16(pA1, &As[b][wid * 1024 + 512 + lane * 8]);
    gload16(pB, &Bs[b][wid * 512 + lane * 8]);
    pA0 += 32; pA1 += 32; pB += 32;
  };

  const int NTK = IDIM / 32;  // 32
  STAGE(0);
  __syncthreads();
  int buf = 0;
  for (int kt = 0; kt < NTK; ++kt) {
    if (kt + 1 < NTK) STAGE(buf ^ 1);
    bf16x8 af[4], bfr[4];
#pragma unroll
    for (int mi = 0; mi < 4; ++mi)
      af[mi] = *(const bf16x8*)&As[buf][swzread(wr + mi * 16 + lr, q)];
#pragma unroll
    for (int ni = 0; ni < 4; ++ni)
      bfr[ni] = *(const bf16x8*)&Bs[buf][swzread(wc + ni * 16 + lr, q)];
#pragma unroll
    for (int mi = 0; mi < 4; ++mi)
#pragma unroll
      for (int ni = 0; ni < 4; ++ni)
        acc[mi][ni] = __builtin_amdgcn_mfma_f32_16x16x32_bf16(af[mi], bfr[ni], acc[mi][ni], 0, 0, 0);
    __syncthreads();
    buf ^= 1;
  }

#pragma unroll
  for (int mi = 0; mi < 4; ++mi) {
#pragma unroll
    for (int ni = 0; ni < 4; ++ni) {
      const int col = nt * 128 + wc + ni * 16 + lr;
#pragma unroll
      for (int r = 0; r < 4; ++r) {
        const int mrow = mt * 256 + wr + mi * 16 + q * 4 + r;
        if (mrow < n_e)
          po[(size_t)(rowbase + mrow) * HDIM + col] = bf1(acc[mi][ni][r]);
      }
    }
  }
}

// ---------------- combine: out[t] = sum_k w_k * po[row_k] -----------------
__global__ __launch_bounds__(256) void combine_kernel(
    const ushort* __restrict__ po, const int* __restrict__ inv,
    const float* __restrict__ tw, float* __restrict__ out)
{
  const int t = blockIdx.x;
  const int r0 = inv[t * 4 + 0], r1 = inv[t * 4 + 1];
  const int r2 = inv[t * 4 + 2], r3 = inv[t * 4 + 3];
  const float w0 = tw[t * 4 + 0], w1 = tw[t * 4 + 1];
  const float w2v = tw[t * 4 + 2], w3 = tw[t * 4 + 3];
  const int i = threadIdx.x;
  uint4 v0 = *(const uint4*)(po + (size_t)r0 * HDIM + i * 8);
  uint4 v1 = *(const uint4*)(po + (size_t)r1 * HDIM + i * 8);
  uint4 v2 = *(const uint4*)(po + (size_t)r2 * HDIM + i * 8);
  uint4 v3 = *(const uint4*)(po + (size_t)r3 * HDIM + i * 8);
  float o[8];
#pragma unroll
  for (int w = 0; w < 4; ++w) {
    const uint32_t a = (&v0.x)[w], b = (&v1.x)[w], c = (&v2.x)[w], d = (&v3.x)[w];
    o[w * 2 + 0] = w0 * __builtin_bit_cast(float, a << 16) +
                   w1 * __builtin_bit_cast(float, b << 16) +
                   w2v * __builtin_bit_cast(float, c << 16) +
                   w3 * __builtin_bit_cast(float, d << 16);
    o[w * 2 + 1] = w0 * __builtin_bit_cast(float, a & 0xffff0000u) +
                   w1 * __builtin_bit_cast(float, b & 0xffff0000u) +
                   w2v * __builtin_bit_cast(float, c & 0xffff0000u) +
                   w3 * __builtin_bit_cast(float, d & 0xffff0000u);
  }
  float4* o4 = (float4*)(out + (size_t)t * HDIM + i * 8);
  o4[0] = (float4){o[0], o[1], o[2], o[3]};
  o4[1] = (float4){o[4], o[5], o[6], o[7]};
}

extern "C" void kernel_launch(void* const* d_in, const int* in_sizes, int n_in,
                              void* d_out, int out_size, void* d_ws, size_t ws_size,
                              hipStream_t stream) {
  const float* x   = (const float*)d_in[0];
  const float* gw  = (const float*)d_in[1];
  const float* w1g = (const float*)d_in[2];
  const float* w1u = (const float*)d_in[3];
  const float* w2  = (const float*)d_in[4];
  float* out = (float*)d_out;

  char* ws = (char*)d_ws;
  ushort* xb    = (ushort*)(ws + 0);
  ushort* wbufG = (ushort*)(ws + 8388608);
  ushort* wbufU = (ushort*)(ws + 75497472);
  ushort* wbuf2 = (ushort*)(ws + 142606336);
  ushort* hbuf  = (ushort*)(ws + 209715200);
  ushort* po    = (ushort*)(ws + 226492416);
  int*    tkid   = (int*)(ws + 260046848);
  float*  tkw    = (float*)(ws + 260046848 + 32768);
  int*    rowTok = (int*)(ws + 260046848 + 65536);
  int*    inv    = (int*)(ws + 260046848 + 98304);
  int*    ctrl   = (int*)(ws + 260177920);
  int* counts  = ctrl;           // 16
  int* offsets = ctrl + 32;      // 17
  int* nWA     = ctrl + 50;      // 1
  int* nWB     = ctrl + 51;      // 1
  int* wlA     = ctrl + 64;      // MAXB1 (1280)
  int* wlB     = ctrl + 64 + MAXB1;  // MAXBB (752)

  router_kernel<<<TTOK / 4 + 2 * NCVT, 256, 0, stream>>>(
      x, gw, xb, tkid, tkw, w1g, wbufG, w1u, wbufU);
  plan_scatter_kernel<<<1, 1024, 0, stream>>>(tkid, counts, offsets, nWA, nWB,
                                              wlA, wlB, rowTok, inv);
  gemm1_kernel<<<MAXB1 + NCVT1, 512, 0, stream>>>(
      xb, wbufG, wbufU, rowTok, counts, offsets, nWA, wlA, hbuf,
      w2, wbuf2);
  gemmB_kernel<<<MAXBB, 512, 0, stream>>>(hbuf, wbuf2, counts, offsets,
                                          nWB, wlB, po);
  combine_kernel<<<TTOK, 256, 0, stream>>>(po, inv, tkw, out);
}